// Round 6
// baseline (76522.498 us; speedup 1.0000x reference)
//
#include <hip/hip_runtime.h>
#include <hip/hip_bf16.h>

typedef __hip_bfloat16 bf16;
typedef _Float16 f16;
typedef _Float16 f16x8 __attribute__((ext_vector_type(8)));
typedef float f32x4 __attribute__((ext_vector_type(4)));
typedef unsigned long long u64;
typedef unsigned short ushort_t;

__device__ __forceinline__ float b2f(bf16 x){ return __bfloat162float(x); }
__device__ __forceinline__ float sigf(float x){ return 1.f/(1.f+expf(-x)); }
__device__ __forceinline__ float splus(float x){ return fmaxf(x,0.f)+log1pf(expf(-fabsf(x))); }
__device__ __forceinline__ float ldf(const void* p, int i, int isf32){
  return isf32 ? ((const float*)p)[i] : __bfloat162float(((const bf16*)p)[i]);
}
// agent-scope coherent ops (bypass per-XCD L2). Proven cross-XCD coherent, no fences.
__device__ __forceinline__ void ast64(u64* p, u64 v){ __hip_atomic_store(p, v, __ATOMIC_RELAXED, __HIP_MEMORY_SCOPE_AGENT); }
__device__ __forceinline__ u64 ald64(u64* p){ return __hip_atomic_load(p, __ATOMIC_RELAXED, __HIP_MEMORY_SCOPE_AGENT); }
__device__ __forceinline__ void ast32(unsigned* p, unsigned v){ __hip_atomic_store(p, v, __ATOMIC_RELAXED, __HIP_MEMORY_SCOPE_AGENT); }
__device__ __forceinline__ unsigned ald32(unsigned* p){ return __hip_atomic_load(p, __ATOMIC_RELAXED, __HIP_MEMORY_SCOPE_AGENT); }

union U4H8 { uint4 u; f16x8 h; };
union U64H4 { u64 u; f16 h[4]; };
union H16 { f16 h; ushort_t s; };

// ---------------- dtype detect ----------------
__global__ void k_detect(const void* __restrict__ emb, int* __restrict__ flag){
  __shared__ float mx[256];
  int tid=threadIdx.x;
  float v = fabsf(__bfloat162float(((const bf16*)emb)[tid]));
  mx[tid]=v; __syncthreads();
  for(int s=128;s>0;s>>=1){ if(tid<s) mx[tid]=fmaxf(mx[tid],mx[tid+s]); __syncthreads(); }
  if(tid==0){ flag[0] = (mx[0]>1000.f) ? 1 : 0; flag[1] = 0; }
}

// ---------------- setup ----------------
// embW[row][v] = b0[row] + sum_k emb[v][k]*Wi0[row][k]   (row-major [2048][256])
__global__ void k_embW(const void* __restrict__ emb, const void* __restrict__ Wi0,
                       const void* __restrict__ b0,
                       const int* __restrict__ flags, float* __restrict__ embW){
  int f=flags[0];
  int row = blockIdx.x;
  __shared__ float w[512];
  for(int k=threadIdx.x;k<512;k+=256) w[k]=ldf(Wi0,row*576+k,f);
  __syncthreads();
  int v = threadIdx.x;
  float acc=ldf(b0,row,f);
  #pragma unroll 4
  for(int k=0;k<512;k++) acc += ldf(emb,v*512+k,f)*w[k];
  embW[row*256+v]=acc;
}

// ---- full layer-0 A-fragment prepack (shared by ALL blocks; L2-streamed) ----
// 128 tiles ti = w*16 + G*4 + tau: rows = G*512 + w*64 + tau*16 + (l&15),
// chunk c=0..17: k=c*32+(l>>4)*8+j; k<512 -> Wh0, k>=512 -> Wi0 lr cols.
// PAF[((ti*18+c)*64+l)*8+j]
__global__ void k_wpkAF(const void* __restrict__ Wh0, const void* __restrict__ Wi0,
                        const int* __restrict__ flags, ushort_t* __restrict__ PAF){
  int f=flags[0];
  int idx=blockIdx.x*256+threadIdx.x;
  if(idx>=1179648) return;
  int j=idx&7, l=(idx>>3)&63, rest=idx>>9;
  int c=rest%18, ti=rest/18;
  int w=ti>>4, G=(ti>>2)&3, tau=ti&3;
  int m=l&15, q4=l>>4;
  int row=G*512 + w*64 + tau*16 + m;
  int k=c*32 + q4*8 + j;
  float val = (k<512)? ldf(Wh0,row*512+k,f) : ldf(Wi0,row*576+k,f);
  H16 hx; hx.h=(f16)val; PAF[idx]=hx.s;
}
// ---- layer-1 per-slice prepack, TRANSPOSED rows (row=dd*4+G) so one acc
// holds all 4 gates of one dim. Block r, wave w owns dims r*32+w*4+[0,4).
// PB1[(((r*8+w)*32+c)*64+l)*8+j]: tr=l&15 -> G=tr&3, dd=tr>>2;
// row=G*512+r*32+w*4+dd; k=c*32+(l>>4)*8+j; k<512 Wi1 (h0), else Wh1 (h1prev).
__global__ void k_wpkB1(const void* __restrict__ Wi1, const void* __restrict__ Wh1,
                        const int* __restrict__ flags, ushort_t* __restrict__ PB){
  int f=flags[0];
  int idx=blockIdx.x*256+threadIdx.x;
  if(idx>=2097152) return;
  int j=idx&7, l=(idx>>3)&63, rest=idx>>9;
  int c=rest&31, t2=rest>>5, w=t2&7, r=t2>>3;
  int tr=l&15, q4=l>>4;
  int G=tr&3, dd=tr>>2;
  int row=G*512 + r*32 + w*4 + dd;
  int k=c*32 + q4*8 + j;
  float val = (k<512)? ldf(Wi1,row*512+k,f) : ldf(Wh1,row*512+k-512,f);
  H16 hx; hx.h=(f16)val; PB[idx]=hx.s;
}

// W_if prepack into MFMA A-frags: 9 tiles of 16 rows (135..143 zero-padded),
// 16 K-chunks. PW[((tile*16+c)*64+l)*8+j]. Also zeroes FL, loads b_ifF.
__global__ void k_wifP(const void* __restrict__ W_if, const void* __restrict__ b_if,
                       const int* __restrict__ flags,
                       ushort_t* __restrict__ PW, float* __restrict__ b_ifF,
                       unsigned* __restrict__ FLz){
  int f=flags[0];
  int idx=blockIdx.x*256+threadIdx.x;
  if(idx<73728){
    int j=idx&7, l=(idx>>3)&63, c=(idx>>9)&15, tile=idx>>13;
    int row=tile*16+(l&15);
    int k=c*32+(l>>4)*8+j;
    float val=(row<135)? ldf(W_if,row*512+k,f) : 0.f;
    H16 hx; hx.h=(f16)val; PW[idx]=hx.s;
  }
  if(idx<64) FLz[idx]=0u;
  if(idx<135) b_ifF[idx]=ldf(b_if,idx,f);
}

__global__ void k_wc(const void* __restrict__ W_fc, const void* __restrict__ W_out,
                     const void* __restrict__ b_out, const void* __restrict__ b_fc,
                     const int* __restrict__ flags,
                     float* __restrict__ Wc, float* __restrict__ bc){
  int f=flags[0];
  int idx=blockIdx.x*256+threadIdx.x;
  int v=idx/576, j=idx-v*576;
  float acc=0.f;
  #pragma unroll 4
  for(int d=0;d<512;d++) acc += ldf(W_fc,v*512+d,f)*ldf(W_out,d*576+j,f);
  Wc[idx]=acc;
  if(j==0){
    float a=ldf(b_fc,v,f);
    for(int d=0;d<512;d++) a += ldf(W_fc,v*512+d,f)*ldf(b_out,d,f);
    bc[v]=a;
  }
}

// ---------------- grouped recurrence: ONE hop per step ----------------
// 4 groups x 16 blocks. Every block redundantly computes the FULL layer-0
// (h0, all 512 dims, its group's 16 batches) streaming PAF from L2 -> h0 is
// never exchanged. Layer-1 stays dim-sliced (block r owns dims r*32+[0,32));
// its h1 slice is the ONLY exchange (beta). P3 redundant per block (proven).
// Gate-grouped MFMA layouts make both nonlinearities register-local (no PR).
// Flag: FL[g*16+r] monotone; after publishing h1(t): flag = t+2.
// Step tt: A1 (Wh0@h0(tt), 256 MFMA — covers hop) -> WAIT(tt+2) -> stage h1(tt)
// -> P3(tt) -> lr frags -> A2 (lr chunks) + nonlin0 -> h0(tt+1) (local LDS)
// -> B (slice) + nonlin1 -> publish h1(tt+1), flag tt+3 -> cat stores.
// GX1 overwrite safety: writer at tt passed WAIT(tt+2) => all blocks staged
// h1(tt-1) (same parity) at tt-1 before their flag tt+2. Verified.
__attribute__((amdgpu_waves_per_eu(2,2)))
__global__ void __launch_bounds__(512) k_dnc3(
    const int* __restrict__ tokens, const void* __restrict__ b1, const int* __restrict__ flags,
    const float* __restrict__ embW, const ushort_t* __restrict__ PAF, const ushort_t* __restrict__ PB1,
    const ushort_t* __restrict__ PW, const float* __restrict__ b_ifF,
    u64* GX1, unsigned* FL,
    bf16* __restrict__ cat)
{
  const int bid = blockIdx.x;
  const int g   = bid>>4, r = bid&15;
  const int tid = threadIdx.x;
  const int wv  = tid>>6, l = tid&63;
  const int lm  = l&15,  q4 = l>>4;
  const int mb  = tid>>5, mu = tid&31;     // machinery (batch, slot)
  const int f32i = flags[0];

  __shared__ __align__(16) u64 H0[2048];   // h0 tile  [kg 0..63][b 0..15][e 0..1]
  __shared__ __align__(16) u64 H1[2048];   // h1 tile
  __shared__ __align__(16) u64 LRf[256];   // lr frags [kg 0..7]
  __shared__ f16  sh_pub[512];
  __shared__ int  tokL[16];
  __shared__ float b_ifL[144];
  __shared__ float xis2[16*149];
  __shared__ float s_mem[1280], s_mem2[1280], s_link[400], s_link2[400];
  __shared__ float s_prec[80], s_prec2[80], s_rwp[320], s_rw[320];
  __shared__ float s_wwp[80], s_ww[80], s_usage[80], s_wl[80];
  __shared__ float s_rl[320], s_fwd[320], s_bwd[320], s_wsum[16];
  __shared__ float rvbuf[1024];

#define WAITG(TGT) do{ if(tid<16){ unsigned _tg=(unsigned)(TGT); int _wd=0; \
    while(ald32(&FL[g*16+tid]) < _tg && _wd<50000000){ __builtin_amdgcn_s_sleep(1); _wd++; } } \
  __syncthreads(); }while(0)
#define PUBF(VAL) do{ __syncthreads(); \
  if(tid==0) ast32(&FL[g*16+r],(unsigned)(VAL)); }while(0)
#define XI(i) xis2[mb*149+(i)]

  const f16x8* H0v=(const f16x8*)H0;
  const f16x8* H1v=(const f16x8*)H1;
  const f16x8* LRv=(const f16x8*)LRf;
  const uint4* PAFv=(const uint4*)PAF;
  const uint4* PB1v=(const uint4*)PB1;
  const uint4* PWv=(const uint4*)PW;

  // layer-1 bias (per-thread, 4 gates of dim1 = r*32+wv*4+q4)
  const int dim1 = r*32 + wv*4 + q4;
  const float b1Li=ldf(b1,dim1,f32i), b1Lf=ldf(b1,512+dim1,f32i),
              b1Lg=ldf(b1,1024+dim1,f32i), b1Lo=ldf(b1,1536+dim1,f32i);

  if(tid<144) b_ifL[tid]=(tid<135)? b_ifF[tid] : 0.f;
  for(int i=tid;i<1280;i+=512) s_mem[i]=0.f;
  for(int i=tid;i<400;i+=512) s_link[i]=0.f;
  for(int i=tid;i<320;i+=512) s_rwp[i]=0.f;
  if(tid<80){ s_prec[tid]=0.f; s_wwp[tid]=0.f; s_usage[tid]=0.f; }
  float c0s[16];
  #pragma unroll
  for(int i=0;i<16;i++) c0s[i]=0.f;
  float c1s=0.f;

  // ---- prologue t=0: h0(0)=f(em(0)), h1(0)=g(h0(0)) ----
  if(tid<16) tokL[tid]=tokens[(g*16+tid)*512];
  __syncthreads();
  {
    int tok=tokL[lm];
    #pragma unroll
    for(int tau=0;tau<4;tau++){
      U64H4 hw;
      #pragma unroll
      for(int reg=0;reg<4;reg++){
        int dim=64*wv+16*tau+4*q4+reg;
        float ei=embW[dim*256+tok];
        float eg=embW[(1024+dim)*256+tok];
        float eo=embW[(1536+dim)*256+tok];
        float c0=sigf(ei)*tanhf(eg);
        c0s[tau*4+reg]=c0;
        hw.h[reg]=(f16)(sigf(eo)*tanhf(c0));
      }
      int kg=8*wv+2*tau+(q4>>1);
      H0[(kg*16+lm)*2+(q4&1)]=hw.u;
    }
  }
  __syncthreads();
  {
    f32x4 acc1=(f32x4){0.f,0.f,0.f,0.f};
    #pragma unroll
    for(int c=0;c<16;c++){
      U4H8 wf; wf.u=PB1v[((r*8+wv)*32+c)*64+l];
      f16x8 bfr=H0v[(c*4+q4)*16+lm];
      acc1=__builtin_amdgcn_mfma_f32_16x16x32_f16(wf.h,bfr,acc1,0,0,0);
    }
    float gi=acc1[0]+b1Li, gg=acc1[2]+b1Lg, go=acc1[3]+b1Lo;
    c1s=sigf(gi)*tanhf(gg);
    sh_pub[(wv*4+q4)*16+lm]=(f16)(sigf(go)*tanhf(c1s));
  }
  __syncthreads();
  if(tid<128){
    int ks=tid>>4, b2=tid&15;
    U64H4 pk;
    #pragma unroll
    for(int i=0;i<4;i++) pk.h[i]=sh_pub[(ks*4+i)*16+b2];
    ast64(&GX1[g*4096+((4*r+(ks>>1))*16+b2)*2+(ks&1)], pk.u);
  }
  PUBF(2u);     // beta(0)

  // ---- main loop ----
  for(int tt=0;tt<512;tt++){
    const int p=tt&1, pn=p^1;
    if(tid<16) tokL[tid]=tokens[(g*16+tid)*512+((tt<511)?tt+1:511)];

    // ===== A1: full layer-0, h0-chunks (covers the beta hop) =====
    f16x8 b0f[16];
    #pragma unroll
    for(int c=0;c<16;c++) b0f[c]=H0v[(c*4+q4)*16+lm];
    f32x4 acc0[16];
    #pragma unroll
    for(int i=0;i<16;i++) acc0[i]=(f32x4){0.f,0.f,0.f,0.f};
    #pragma unroll
    for(int G=0;G<4;G++){
      #pragma unroll
      for(int tau=0;tau<4;tau++){
        #pragma unroll
        for(int c=0;c<16;c++){
          U4H8 wf; wf.u=PAFv[((wv*16+G*4+tau)*18+c)*64+l];
          acc0[G*4+tau]=__builtin_amdgcn_mfma_f32_16x16x32_f16(wf.h,b0f[c],acc0[G*4+tau],0,0,0);
        }
      }
    }

    WAITG(tt+2u);

    // stage h1(tt)
    {
      u64 s0=ald64(&GX1[g*4096+p*2048+tid      ]);
      u64 s1=ald64(&GX1[g*4096+p*2048+tid+512  ]);
      u64 s2=ald64(&GX1[g*4096+p*2048+tid+1024 ]);
      u64 s3=ald64(&GX1[g*4096+p*2048+tid+1536 ]);
      H1[tid]=s0; H1[tid+512]=s1; H1[tid+1024]=s2; H1[tid+1536]=s3;
    }
    __syncthreads();

    // ===== P3(tt): xi = W_if @ h1 via MFMA, then machinery (redundant) =====
    {
      f32x4 xa=(f32x4){0.f,0.f,0.f,0.f};
      #pragma unroll
      for(int hh=0;hh<4;hh++){
        uint4 w4[4];
        #pragma unroll
        for(int cc=0;cc<4;cc++) w4[cc]=PWv[(wv*16+hh*4+cc)*64+l];
        #pragma unroll
        for(int cc=0;cc<4;cc++){
          U4H8 t4; t4.u=w4[cc];
          f16x8 bfr=H1v[((hh*4+cc)*4+q4)*16+lm];
          xa=__builtin_amdgcn_mfma_f32_16x16x32_f16(t4.h,bfr,xa,0,0,0);
        }
      }
      #pragma unroll
      for(int reg=0;reg<4;reg++){
        int row=wv*16+q4*4+reg;
        xis2[lm*149+row]=xa[reg]+b_ifL[row];
      }
      if(wv==0){
        f32x4 xb=(f32x4){0.f,0.f,0.f,0.f};
        #pragma unroll
        for(int hh=0;hh<4;hh++){
          uint4 w4[4];
          #pragma unroll
          for(int cc=0;cc<4;cc++) w4[cc]=PWv[(128+hh*4+cc)*64+l];
          #pragma unroll
          for(int cc=0;cc<4;cc++){
            U4H8 t4; t4.u=w4[cc];
            f16x8 bfr=H1v[((hh*4+cc)*4+q4)*16+lm];
            xb=__builtin_amdgcn_mfma_f32_16x16x32_f16(t4.h,bfr,xb,0,0,0);
          }
        }
        #pragma unroll
        for(int reg=0;reg<4;reg++){
          int row=128+q4*4+reg;
          xis2[lm*149+row]=xb[reg]+b_ifL[row];
        }
      }
    }
    __syncthreads();

    // M1
    if(mu<5){
      int m=mu;
      float u=s_usage[mb*5+m]+(1.f-s_usage[mb*5+m])*s_wwp[mb*5+m];
      float psi=1.f;
      #pragma unroll
      for(int rr=0;rr<4;rr++) psi *= 1.f - sigf(XI(117+rr))*s_rwp[mb*20+rr*5+m];
      u*=psi; s_usage[mb*5+m]=u;
      float nm=0.f,dt=0.f,nk=0.f;
      #pragma unroll
      for(int w=0;w<16;w++){
        float mv=s_mem[mb*80+m*16+w], kv=tanhf(XI(68+w));
        nm+=mv*mv; dt+=mv*kv; nk+=kv*kv;
      }
      float sim=dt/((sqrtf(nm)+1e-6f)*(sqrtf(nk)+1e-6f));
      s_wl[mb*5+m]=sim*splus(XI(84));
    }
    __syncthreads();
    // M2
    if(mu==0){
      float mx=-1e30f;
      for(int m=0;m<5;m++) mx=fmaxf(mx,s_wl[mb*5+m]);
      float e[5]; float s=0.f;
      for(int m=0;m<5;m++){ e[m]=expf(s_wl[mb*5+m]-mx); s+=e[m]; }
      float u[5]; int id[5];
      for(int m=0;m<5;m++){ u[m]=1e-6f+(1.f-1e-6f)*s_usage[mb*5+m]; id[m]=m; }
      for(int i=1;i<5;i++){
        float uv=u[i]; int iv=id[i]; int j=i-1;
        while(j>=0&&u[j]>uv){u[j+1]=u[j];id[j+1]=id[j];j--;}
        u[j+1]=uv; id[j+1]=iv;
      }
      float alm[5]; float prod=1.f;
      for(int i=0;i<5;i++){ alm[id[i]]=(1.f-u[i])*prod; prod*=u[i]; }
      float ag=sigf(XI(121)), wgg=sigf(XI(122));
      float wsum=0.f;
      for(int m=0;m<5;m++){
        float wcw=e[m]/s;
        float w_=wgg*(ag*alm[m]+(1.f-ag)*wcw);
        s_ww[mb*5+m]=w_; wsum+=w_;
      }
      s_wsum[mb]=wsum;
    }
    __syncthreads();
    // M3
    for(int k=mu;k<80;k+=32){
      int m=k>>4,w=k&15;
      float er=sigf(XI(85+w)), wv2=tanhf(XI(101+w));
      float w_=s_ww[mb*5+m];
      s_mem2[mb*80+k]=s_mem[mb*80+k]*(1.f-w_*er)+w_*wv2;
    }
    if(mu<25){
      int i=mu/5, j=mu-5*i;
      s_link2[mb*25+mu]=(i==j)?0.f:((1.f-s_ww[mb*5+i]-s_ww[mb*5+j])*s_link[mb*25+mu]+s_ww[mb*5+i]*s_prec[mb*5+j]);
    } else if(mu<30){
      int j=mu-25;
      s_prec2[mb*5+j]=(1.f-s_wsum[mb])*s_prec[mb*5+j]+s_ww[mb*5+j];
    }
    __syncthreads();
    // M4
    if(mu<20){
      int rr=mu/5, m=mu-5*rr;
      float nm=0.f,dt=0.f,nk=0.f;
      #pragma unroll
      for(int w=0;w<16;w++){
        float mv=s_mem2[mb*80+m*16+w], kv=tanhf(XI(rr*16+w));
        nm+=mv*mv; dt+=mv*kv; nk+=kv*kv;
      }
      float sim=dt/((sqrtf(nm)+1e-6f)*(sqrtf(nk)+1e-6f));
      s_rl[mb*20+mu]=sim*splus(XI(64+rr));
      float af=0.f, ab=0.f;
      #pragma unroll
      for(int j=0;j<5;j++) af+=s_link2[mb*25+m*5+j]*s_rwp[mb*20+rr*5+j];
      #pragma unroll
      for(int i=0;i<5;i++) ab+=s_link2[mb*25+i*5+m]*s_rwp[mb*20+rr*5+i];
      s_fwd[mb*20+rr*5+m]=af;
      s_bwd[mb*20+rr*5+m]=ab;
    }
    __syncthreads();
    // M5
    if(mu<20){
      int rr=mu/5;
      float mx=-1e30f;
      for(int m=0;m<5;m++) mx=fmaxf(mx,s_rl[mb*20+rr*5+m]);
      float s=0.f;
      for(int m=0;m<5;m++) s+=expf(s_rl[mb*20+rr*5+m]-mx);
      float rcw=expf(s_rl[mb*20+mu]-mx)/s;
      float q0=XI(123+3*rr),q1=XI(124+3*rr),q2=XI(125+3*rr);
      float m3=fmaxf(q0,fmaxf(q1,q2));
      float e0=expf(q0-m3),e1=expf(q1-m3),e2=expf(q2-m3);
      float inv=1.f/(e0+e1+e2);
      s_rw[mb*20+mu]=(e0*s_bwd[mb*20+mu]+e1*s_fwd[mb*20+mu]+e2*rcw)*inv;
    }
    __syncthreads();
    // M6
    for(int k=mu;k<64;k+=32){
      int rr=k>>4,w=k&15;
      float a=0.f;
      #pragma unroll
      for(int m=0;m<5;m++) a+=s_rw[mb*20+rr*5+m]*s_mem2[mb*80+m*16+w];
      rvbuf[mb*64+k]=a;
    }
    for(int k=mu;k<80;k+=32) s_mem[mb*80+k]=s_mem2[mb*80+k];
    if(mu<25) s_link[mb*25+mu]=s_link2[mb*25+mu];
    else if(mu<30) s_prec[mb*5+mu-25]=s_prec2[mb*5+mu-25];
    if(mu<20) s_rwp[mb*20+mu]=s_rw[mb*20+mu];
    if(mu>=27&&mu<32){ int m=mu-27; s_wwp[mb*5+m]=s_ww[mb*5+m]; }
    __syncthreads();

    if(tt==511){
      int cb=((g*16+r)*512+tt)*576;
      if(tid<128){
        int kg=tid>>1, e=tid&1;
        U64H4 pv; pv.u=H1[(kg*16+r)*2+e];
        #pragma unroll
        for(int i=0;i<4;i++){
          float x=(float)pv.h[i];
          cat[cb+kg*8+e*4+i]=__float2bfloat16(fminf(fmaxf(x,-20.f),20.f));
        }
      }
      if(tid<64) cat[cb+512+tid]=__float2bfloat16(rvbuf[r*64+tid]);
      break;
    }

    // build lr B-frags
    if(tid<256){
      int kg=tid>>5, rem=tid&31, b2=rem>>1, e=rem&1;
      U64H4 pk;
      #pragma unroll
      for(int i=0;i<4;i++) pk.h[i]=(f16)rvbuf[b2*64 + kg*8+e*4+i];
      LRf[(kg*16+b2)*2+e]=pk.u;
    }
    __syncthreads();

    // ===== A2: lr chunks, then register-local nonlin0 -> h0(tt+1) =====
    #pragma unroll
    for(int c2=0;c2<2;c2++){
      f16x8 lrb=LRv[(c2*4+q4)*16+lm];
      #pragma unroll
      for(int G=0;G<4;G++){
        #pragma unroll
        for(int tau=0;tau<4;tau++){
          U4H8 wf; wf.u=PAFv[((wv*16+G*4+tau)*18+16+c2)*64+l];
          acc0[G*4+tau]=__builtin_amdgcn_mfma_f32_16x16x32_f16(wf.h,lrb,acc0[G*4+tau],0,0,0);
        }
      }
    }
    {
      int tok=tokL[lm];
      #pragma unroll
      for(int tau=0;tau<4;tau++){
        U64H4 hw;
        #pragma unroll
        for(int reg=0;reg<4;reg++){
          int dim=64*wv+16*tau+4*q4+reg;
          float ei=embW[dim*256+tok];
          float ef=embW[(512+dim)*256+tok];
          float eg=embW[(1024+dim)*256+tok];
          float eo=embW[(1536+dim)*256+tok];
          float gi=acc0[tau][reg]+ei;
          float gf=acc0[4+tau][reg]+ef;
          float gg=acc0[8+tau][reg]+eg;
          float go=acc0[12+tau][reg]+eo;
          float c0=sigf(gf)*c0s[tau*4+reg]+sigf(gi)*tanhf(gg);
          c0s[tau*4+reg]=c0;
          hw.h[reg]=(f16)(sigf(go)*tanhf(c0));
        }
        int kg=8*wv+2*tau+(q4>>1);
        H0[(kg*16+lm)*2+(q4&1)]=hw.u;
      }
    }
    __syncthreads();

    // ===== B: layer-1 slice + nonlin1 -> h1(tt+1) =====
    {
      f32x4 acc1=(f32x4){0.f,0.f,0.f,0.f};
      #pragma unroll
      for(int c=0;c<16;c++){
        U4H8 wf; wf.u=PB1v[((r*8+wv)*32+c)*64+l];
        f16x8 bfr=H0v[(c*4+q4)*16+lm];
        acc1=__builtin_amdgcn_mfma_f32_16x16x32_f16(wf.h,bfr,acc1,0,0,0);
      }
      #pragma unroll
      for(int c=16;c<32;c++){
        U4H8 wf; wf.u=PB1v[((r*8+wv)*32+c)*64+l];
        f16x8 bfr=H1v[((c-16)*4+q4)*16+lm];
        acc1=__builtin_amdgcn_mfma_f32_16x16x32_f16(wf.h,bfr,acc1,0,0,0);
      }
      float gi=acc1[0]+b1Li, gf=acc1[1]+b1Lf, gg=acc1[2]+b1Lg, go=acc1[3]+b1Lo;
      float c1=sigf(gf)*c1s+sigf(gi)*tanhf(gg);
      c1s=c1;
      sh_pub[(wv*4+q4)*16+lm]=(f16)(sigf(go)*tanhf(c1));
    }
    __syncthreads();
    if(tid<128){
      int ks=tid>>4, b2=tid&15;
      U64H4 pk;
      #pragma unroll
      for(int i=0;i<4;i++) pk.h[i]=sh_pub[(ks*4+i)*16+b2];
      ast64(&GX1[g*4096+pn*2048+((4*r+(ks>>1))*16+b2)*2+(ks&1)], pk.u);
    }
    PUBF(tt+3u);     // beta(tt+1)

    // cat stores for tt (off critical path)
    {
      int cb=((g*16+r)*512+tt)*576;
      if(tid<128){
        int kg=tid>>1, e=tid&1;
        U64H4 pv; pv.u=H1[(kg*16+r)*2+e];
        #pragma unroll
        for(int i=0;i<4;i++){
          float x=(float)pv.h[i];
          cat[cb+kg*8+e*4+i]=__float2bfloat16(fminf(fmaxf(x,-20.f),20.f));
        }
      }
      if(tid<64) cat[cb+512+tid]=__float2bfloat16(rvbuf[r*64+tid]);
    }
  }
#undef WAITG
#undef PUBF
#undef XI
}

// ---------------- final output GEMM (f32 out) ----------------
__global__ void __launch_bounds__(256) k_out(const bf16* __restrict__ cat,
                                             const float* __restrict__ Wc,
                                             const float* __restrict__ bc,
                                             float* __restrict__ outp){
  int t0=blockIdx.x*64, v0=blockIdx.y*64, b=blockIdx.z;
  __shared__ float As[64][33];
  __shared__ float Bs[32][65];
  int tid=threadIdx.x;
  int ti=tid>>4, vi=tid&15;
  float acc[4][4]={};
  for(int k0=0;k0<576;k0+=32){
    for(int i=tid;i<64*32;i+=256){
      int rr=i>>5,k=i&31;
      As[rr][k]=b2f(cat[(b*512+t0+rr)*576+k0+k]);
    }
    for(int i=tid;i<64*32;i+=256){
      int v=i>>5,k=i&31;
      Bs[k][v]=Wc[(v0+v)*576+k0+k];
    }
    __syncthreads();
    #pragma unroll 8
    for(int kk=0;kk<32;kk++){
      float av[4],bv[4];
      #pragma unroll
      for(int x=0;x<4;x++) av[x]=As[ti*4+x][kk];
      #pragma unroll
      for(int y=0;y<4;y++) bv[y]=Bs[kk][vi*4+y];
      #pragma unroll
      for(int x=0;x<4;x++)
        #pragma unroll
        for(int y=0;y<4;y++) acc[x][y]+=av[x]*bv[y];
    }
    __syncthreads();
  }
  #pragma unroll
  for(int y=0;y<4;y++){
    int v=v0+vi*4+y;
    float bcv=bc[v];
    #pragma unroll
    for(int x=0;x<4;x++){
      int tt=t0+ti*4+x;
      outp[(b*256+v)*512+tt]=acc[x][y]+bcv;
    }
  }
}

extern "C" void kernel_launch(void* const* d_in, const int* in_sizes, int n_in,
                              void* d_out, int out_size, void* d_ws, size_t ws_size,
                              hipStream_t stream) {
  const int*  tokens = (const int*) d_in[0];
  const void* emb    = d_in[1];
  const void* Wi0    = d_in[2];
  const void* Wh0    = d_in[3];
  const void* b0     = d_in[4];
  const void* Wi1    = d_in[5];
  const void* Wh1    = d_in[6];
  const void* b1     = d_in[7];
  const void* W_if   = d_in[8];
  const void* b_if   = d_in[9];
  const void* W_out  = d_in[10];
  const void* b_out  = d_in[11];
  const void* W_fc   = d_in[12];
  const void* b_fc   = d_in[13];

  static const int expect[14] = {64*512, 256*512, 2048*576, 2048*512, 2048,
                                 2048*512, 2048*512, 2048, 135*512, 135,
                                 512*576, 512, 256*512, 256};
  bool ok = (n_in == 14);
  if(ok) for(int i=0;i<14;i++) if(in_sizes[i]!=expect[i]) ok=false;

  int*      flags = (int*)d_ws;                   // [0]=dtype flag
  float*    embW  = (float*)d_ws + 64;            // 2048*256
  ushort_t* PAF   = (ushort_t*)(embW + 524288);   // 1179648 f16 (region 1310720; FL at +1179648)
  ushort_t* PB1   = PAF + 1310720;                // 2097152 f16
  float*    Wreg  = (float*)(PB1 + 2097152);      // PW (73728 f16) lives here
  float*    b_ifF = Wreg + 69632;                 // 160
  float*    Wc    = b_ifF + 160;                  // 147456
  float*    bc    = Wc + 147456;                  // 256
  u64*      GX0   = (u64*)(bc + 256);             // 16384 u64 (unused, layout keep)
  u64*      GX1   = GX0 + 16384;                  // 16384 u64 = [4 grp][2 ph][2048]
  u64*      GXL   = GX1 + 16384;                  // 2048 u64 (unused)
  bf16*     cat   = (bf16*)(GXL + 2048);          // 64*512*576
  unsigned* FL    = (unsigned*)(PAF + 1179648);   // 64 dwords: 4 groups x 16 flags
  ushort_t* PW    = (ushort_t*)Wreg;              // 73728 f16

  size_t need = 9783168ull + 278528ull + 37748736ull;   // = 47,810,432 B
  if(!ok || ws_size < need){
    hipMemsetAsync(d_out, 0, (size_t)out_size*4, stream);
    return;
  }

  k_detect<<<dim3(1), dim3(256), 0, stream>>>(emb, flags);
  k_embW<<<dim3(2048), dim3(256), 0, stream>>>(emb, Wi0, b0, flags, embW);
  k_wpkAF<<<dim3(4608), dim3(256), 0, stream>>>(Wh0, Wi0, flags, PAF);
  k_wpkB1<<<dim3(8192), dim3(256), 0, stream>>>(Wi1, Wh1, flags, PB1);
  k_wifP<<<dim3(288), dim3(256), 0, stream>>>(W_if, b_if, flags, PW, b_ifF, FL);
  k_wc  <<<dim3(576),  dim3(256), 0, stream>>>(W_fc, W_out, b_out, b_fc, flags, Wc, bc);

  void* kargs[] = {
    (void*)&tokens, (void*)&b1, (void*)&flags,
    (void*)&embW, (void*)&PAF, (void*)&PB1,
    (void*)&PW, (void*)&b_ifF,
    (void*)&GX1, (void*)&FL,
    (void*)&cat
  };
  hipLaunchCooperativeKernel((const void*)k_dnc3, dim3(64), dim3(512), kargs, 0, stream);

  k_out<<<dim3(8,4,64), dim3(256), 0, stream>>>(cat, Wc, bc, (float*)d_out);
}

// Round 7
// 12504.794 us; speedup vs baseline: 6.1195x; 6.1195x over previous
//
#include <hip/hip_runtime.h>
#include <hip/hip_bf16.h>

typedef __hip_bfloat16 bf16;
typedef _Float16 f16;
typedef _Float16 f16x8 __attribute__((ext_vector_type(8)));
typedef float f32x4 __attribute__((ext_vector_type(4)));
typedef unsigned long long u64;
typedef unsigned short ushort_t;

__device__ __forceinline__ float b2f(bf16 x){ return __bfloat162float(x); }
__device__ __forceinline__ float sigf(float x){ return 1.f/(1.f+expf(-x)); }
__device__ __forceinline__ float splus(float x){ return fmaxf(x,0.f)+log1pf(expf(-fabsf(x))); }
__device__ __forceinline__ float ldf(const void* p, int i, int isf32){
  return isf32 ? ((const float*)p)[i] : __bfloat162float(((const bf16*)p)[i]);
}
// agent-scope coherent ops (bypass per-XCD L2). Proven cross-XCD coherent, no fences.
__device__ __forceinline__ void ast64(u64* p, u64 v){ __hip_atomic_store(p, v, __ATOMIC_RELAXED, __HIP_MEMORY_SCOPE_AGENT); }
__device__ __forceinline__ u64 ald64(u64* p){ return __hip_atomic_load(p, __ATOMIC_RELAXED, __HIP_MEMORY_SCOPE_AGENT); }
__device__ __forceinline__ void ast32(unsigned* p, unsigned v){ __hip_atomic_store(p, v, __ATOMIC_RELAXED, __HIP_MEMORY_SCOPE_AGENT); }
__device__ __forceinline__ unsigned ald32(unsigned* p){ return __hip_atomic_load(p, __ATOMIC_RELAXED, __HIP_MEMORY_SCOPE_AGENT); }

union U4H8 { uint4 u; f16x8 h; };
union U64H4 { u64 u; f16 h[4]; };
union H16 { f16 h; ushort_t s; };

// ---------------- dtype detect ----------------
__global__ void k_detect(const void* __restrict__ emb, int* __restrict__ flag){
  __shared__ float mx[256];
  int tid=threadIdx.x;
  float v = fabsf(__bfloat162float(((const bf16*)emb)[tid]));
  mx[tid]=v; __syncthreads();
  for(int s=128;s>0;s>>=1){ if(tid<s) mx[tid]=fmaxf(mx[tid],mx[tid+s]); __syncthreads(); }
  if(tid==0){ flag[0] = (mx[0]>1000.f) ? 1 : 0; flag[1] = 0; }
}

// ---------------- setup ----------------
// embW[row][v] = b0[row] + sum_k emb[v][k]*Wi0[row][k]   (row-major [2048][256])
__global__ void k_embW(const void* __restrict__ emb, const void* __restrict__ Wi0,
                       const void* __restrict__ b0,
                       const int* __restrict__ flags, float* __restrict__ embW){
  int f=flags[0];
  int row = blockIdx.x;
  __shared__ float w[512];
  for(int k=threadIdx.x;k<512;k+=256) w[k]=ldf(Wi0,row*576+k,f);
  __syncthreads();
  int v = threadIdx.x;
  float acc=ldf(b0,row,f);
  #pragma unroll 4
  for(int k=0;k<512;k++) acc += ldf(emb,v*512+k,f)*w[k];
  embW[row*256+v]=acc;
}

// ---- weight prepack (ROUND-5 group design: per-block slices, L2-resident) ----
// Block (g,r): r owns hidden dims [32r,32r+32) -> 128 gate rows. Wave w=G*2+h owns
// rows G*512 + r*32 + h*16 + [0,16). A-frag 16x16x32 f16: lane l row (l&15),
// k=(l>>4)*8+j.  PA chunks c=0..17: k<512 Wh0, k>=512 Wi0 lr cols.
__global__ void k_wpkA(const void* __restrict__ Wh0, const void* __restrict__ Wi0,
                       const int* __restrict__ flags, ushort_t* __restrict__ PA){
  int f=flags[0];
  int idx=blockIdx.x*256+threadIdx.x;
  if(idx>=1179648) return;
  int j=idx&7, l=(idx>>3)&63, rest=idx>>9;
  int c=rest%18, t2=rest/18, w=t2&7, r=t2>>3;
  int G=w>>1, hh=w&1, m=l&15, q4=l>>4;
  int row=G*512 + r*32 + hh*16 + m;
  int k=c*32 + q4*8 + j;
  float val = (k<512)? ldf(Wh0,row*512+k,f) : ldf(Wi0,row*576+k,f);
  H16 hx; hx.h=(f16)val; PA[idx]=hx.s;
}
// PB chunks c=0..31: k<512 Wi1 (h0(t)), k>=512 Wh1 (h1(t-1)).
__global__ void k_wpkB(const void* __restrict__ Wi1, const void* __restrict__ Wh1,
                       const int* __restrict__ flags, ushort_t* __restrict__ PB){
  int f=flags[0];
  int idx=blockIdx.x*256+threadIdx.x;
  if(idx>=2097152) return;
  int j=idx&7, l=(idx>>3)&63, rest=idx>>9;
  int c=rest&31, t2=rest>>5, w=t2&7, r=t2>>3;
  int G=w>>1, hh=w&1, m=l&15, q4=l>>4;
  int row=G*512 + r*32 + hh*16 + m;
  int k=c*32 + q4*8 + j;
  float val = (k<512)? ldf(Wi1,row*512+k,f) : ldf(Wh1,row*512+k-512,f);
  H16 hx; hx.h=(f16)val; PB[idx]=hx.s;
}

// W_if prepack into MFMA A-frags: 9 tiles of 16 rows (135..143 zero-padded),
// 16 K-chunks. PW[((tile*16+c)*64+l)*8+j]. Also zeroes FL, loads b_ifF.
__global__ void k_wifP(const void* __restrict__ W_if, const void* __restrict__ b_if,
                       const int* __restrict__ flags,
                       ushort_t* __restrict__ PW, float* __restrict__ b_ifF,
                       unsigned* __restrict__ FLz){
  int f=flags[0];
  int idx=blockIdx.x*256+threadIdx.x;
  if(idx<73728){
    int j=idx&7, l=(idx>>3)&63, c=(idx>>9)&15, tile=idx>>13;
    int row=tile*16+(l&15);
    int k=c*32+(l>>4)*8+j;
    float val=(row<135)? ldf(W_if,row*512+k,f) : 0.f;
    H16 hx; hx.h=(f16)val; PW[idx]=hx.s;
  }
  if(idx<64) FLz[idx]=0u;
  if(idx<135) b_ifF[idx]=ldf(b_if,idx,f);
}

__global__ void k_wc(const void* __restrict__ W_fc, const void* __restrict__ W_out,
                     const void* __restrict__ b_out, const void* __restrict__ b_fc,
                     const int* __restrict__ flags,
                     float* __restrict__ Wc, float* __restrict__ bc){
  int f=flags[0];
  int idx=blockIdx.x*256+threadIdx.x;
  int v=idx/576, j=idx-v*576;
  float acc=0.f;
  #pragma unroll 4
  for(int d=0;d<512;d++) acc += ldf(W_fc,v*512+d,f)*ldf(W_out,d*576+j,f);
  Wc[idx]=acc;
  if(j==0){
    float a=ldf(b_fc,v,f);
    for(int d=0;d<512;d++) a += ldf(W_fc,v*512+d,f)*ldf(b_out,d,f);
    bc[v]=a;
  }
}

// ---------------- grouped recurrence (ROUND-5 2-hop) + micro-opts ----------------
// 4 groups x 16 blocks; block (g,r) owns dims [32r,32r+32); per-XCD L2 holds the
// 2 distinct r-slices it serves (no HBM thrash; FETCH ~0.3GB — round-6 lesson).
// P3 machinery redundant per block (all 16 batches); xi via MFMA vs staged h1.
// Flags: FL[g*16+r] monotone: init=1, alpha(t)=2t+2, beta(t)=2t+3.
// NEW vs round 5: (1) M1..M6 are wave-local (one half-wave per batch) ->
// inter-M syncthreads replaced with wave_barrier (free); (2) M2 allocation via
// 5-lane stable rank instead of 1-lane insertion sort; (3) B-phase h0-chunk
// weight frags prefetched into regs BEFORE the alpha wait (L2 latency hidden
// in the hop); A2 lr-frags prefetched before the beta wait.
__attribute__((amdgpu_waves_per_eu(2,2)))
__global__ void __launch_bounds__(512) k_dnc3(
    const int* __restrict__ tokens, const void* __restrict__ b1, const int* __restrict__ flags,
    const float* __restrict__ embW, const ushort_t* __restrict__ PA, const ushort_t* __restrict__ PB,
    const ushort_t* __restrict__ PW, const float* __restrict__ b_ifF,
    u64* GX0, u64* GX1, unsigned* FL,
    bf16* __restrict__ cat)
{
  const int bid = blockIdx.x;
  const int g   = bid>>4, r = bid&15;
  const int tid = threadIdx.x;
  const int wv  = tid>>6, l = tid&63;
  const int lm  = l&15,  q4 = l>>4;
  const int d   = tid>>4, bb = tid&15;     // nonlinearity mapping (dim, batch)
  const int mb  = tid>>5, mu = tid&31;     // machinery mapping (batch, slot)
  const int f32i = flags[0];

  __shared__ __align__(16) u64 HB[4352];   // [0..2047] h0 | [2048..4095] h1 | [4096..4351] lr frags
  __shared__ float PR[128*17];
  __shared__ f16  sh_pub[512];
  __shared__ float sh_b1[128];
  __shared__ float b_ifL[144];
  __shared__ float xis2[16*149];
  __shared__ float s_mem[1280], s_mem2[1280], s_link[400], s_link2[400];
  __shared__ float s_prec[80], s_prec2[80], s_rwp[320], s_rw[320];
  __shared__ float s_wwp[80], s_ww[80], s_usage[80], s_wl[80];
  __shared__ float s_rl[320], s_fwd[320], s_bwd[320], s_wsum[16];
  __shared__ float rvbuf[1024];

#define WAITG(TGT) do{ if(tid<16){ unsigned _tg=(unsigned)(TGT); int _wd=0; \
    while(ald32(&FL[g*16+tid]) < _tg && _wd<50000000){ __builtin_amdgcn_s_sleep(1); _wd++; } } \
  __syncthreads(); }while(0)
#define PUBF(VAL) do{ __syncthreads(); \
  if(tid==0) ast32(&FL[g*16+r],(unsigned)(VAL)); }while(0)
#define XI(i) xis2[mb*149+(i)]
#define WB() __builtin_amdgcn_wave_barrier()

  const f16x8* HBv=(const f16x8*)HB;
  const uint4* PAv=(const uint4*)PA;
  const uint4* PBv=(const uint4*)PB;
  const uint4* PWv=(const uint4*)PW;

  if(tid<128) sh_b1[tid]=ldf(b1,(tid>>5)*512 + r*32 + (tid&31), f32i);
  if(tid<144) b_ifL[tid]=(tid<135)? b_ifF[tid] : 0.f;
  for(int i=tid;i<1280;i+=512) s_mem[i]=0.f;
  for(int i=tid;i<400;i+=512) s_link[i]=0.f;
  for(int i=tid;i<320;i+=512) s_rwp[i]=0.f;
  if(tid<80){ s_prec[tid]=0.f; s_wwp[tid]=0.f; s_usage[tid]=0.f; }
  float c0s=0.f, c1s=0.f;

  // ---- prologue: t=0 (h0(0)=f(em(0)); recurrent/lr terms zero) ----
  {
    int tok0=tokens[(g*16+bb)*512];
    int base0=(r*32+d)*256+tok0;
    float e0=embW[base0], e2=embW[262144+base0], e3=embW[393216+base0];
    c0s = sigf(e0)*tanhf(e2);
    float h0v = sigf(e3)*tanhf(c0s);
    sh_pub[d*16+bb]=(f16)h0v;
  }
  __syncthreads();
  if(tid<128){
    int ks=tid>>4, b2=tid&15;
    U64H4 pk;
    #pragma unroll
    for(int i=0;i<4;i++) pk.h[i]=sh_pub[(ks*4+i)*16+b2];
    ast64(&GX0[g*4096+((4*r+(ks>>1))*16+b2)*2+(ks&1)], pk.u);
  }
  PUBF(2u);            // alpha(0)
  WAITG(2u);
  {
    u64 s0=ald64(&GX0[g*4096+tid      ]);
    u64 s1=ald64(&GX0[g*4096+tid+512  ]);
    u64 s2=ald64(&GX0[g*4096+tid+1024 ]);
    u64 s3=ald64(&GX0[g*4096+tid+1536 ]);
    HB[tid]=s0; HB[tid+512]=s1; HB[tid+1024]=s2; HB[tid+1536]=s3;
  }
  __syncthreads();
  {
    f32x4 accB=(f32x4){0.f,0.f,0.f,0.f};
    #pragma unroll
    for(int c=0;c<16;c++){
      U4H8 wf; wf.u=PBv[((r*8+wv)*32+c)*64+l];
      f16x8 bfr=HBv[(c*4+q4)*16+lm];
      accB=__builtin_amdgcn_mfma_f32_16x16x32_f16(wf.h,bfr,accB,0,0,0);
    }
    #pragma unroll
    for(int reg=0;reg<4;reg++) PR[(wv*16+q4*4+reg)*17+lm]=accB[reg];
  }
  __syncthreads();
  {
    float gi=PR[(d    )*17+bb]+sh_b1[d];
    float gg=PR[(64+d )*17+bb]+sh_b1[64+d];
    float go=PR[(96+d )*17+bb]+sh_b1[96+d];
    c1s = sigf(gi)*tanhf(gg);
    float h=sigf(go)*tanhf(c1s);
    sh_pub[d*16+bb]=(f16)h;
  }
  __syncthreads();
  if(tid<128){
    int ks=tid>>4, b2=tid&15;
    U64H4 pk;
    #pragma unroll
    for(int i=0;i<4;i++) pk.h[i]=sh_pub[(ks*4+i)*16+b2];
    ast64(&GX1[g*4096+((4*r+(ks>>1))*16+b2)*2+(ks&1)], pk.u);
  }
  PUBF(3u);            // beta(0)

  // ---- main loop ----
  for(int tt=0;tt<512;tt++){
    const int p=tt&1, pn=p^1;

    // cover1: A(tt+1) p1 on h0(tt) resident in HB[0..2047]
    f32x4 accA=(f32x4){0.f,0.f,0.f,0.f};
    #pragma unroll
    for(int c=0;c<16;c++){
      U4H8 wf; wf.u=PAv[((r*8+wv)*18+c)*64+l];
      f16x8 bfr=HBv[(c*4+q4)*16+lm];
      accA=__builtin_amdgcn_mfma_f32_16x16x32_f16(wf.h,bfr,accA,0,0,0);
    }
    // prefetch em(tt+1) and the A2 lr-frag weights (independent of the hop)
    float em0,em1,em2,em3;
    {
      int tn=(tt<511)?tt+1:511;
      int tok=tokens[(g*16+bb)*512+tn];
      int base=(r*32+d)*256+tok;
      em0=embW[base]; em1=embW[131072+base]; em2=embW[262144+base]; em3=embW[393216+base];
    }
    uint4 pfA2[2];
    #pragma unroll
    for(int c2=0;c2<2;c2++) pfA2[c2]=PAv[((r*8+wv)*18+16+c2)*64+l];

    WAITG(2*tt+3);     // beta(tt)

    // stage h1(tt) -> HB[2048..4095]
    {
      u64 s0=ald64(&GX1[g*4096+p*2048+tid      ]);
      u64 s1=ald64(&GX1[g*4096+p*2048+tid+512  ]);
      u64 s2=ald64(&GX1[g*4096+p*2048+tid+1024 ]);
      u64 s3=ald64(&GX1[g*4096+p*2048+tid+1536 ]);
      HB[2048+tid]=s0; HB[2048+tid+512]=s1; HB[2048+tid+1024]=s2; HB[2048+tid+1536]=s3;
    }
    __syncthreads();

    // ====== P3(tt): xi = W_if @ h1 via MFMA (redundant per block) ======
    {
      f32x4 xa=(f32x4){0.f,0.f,0.f,0.f};
      #pragma unroll
      for(int hh=0;hh<4;hh++){
        uint4 w4[4];
        #pragma unroll
        for(int cc=0;cc<4;cc++) w4[cc]=PWv[(wv*16+hh*4+cc)*64+l];
        #pragma unroll
        for(int cc=0;cc<4;cc++){
          U4H8 t4; t4.u=w4[cc];
          f16x8 bfr=HBv[1024+((hh*4+cc)*4+q4)*16+lm];
          xa=__builtin_amdgcn_mfma_f32_16x16x32_f16(t4.h,bfr,xa,0,0,0);
        }
      }
      #pragma unroll
      for(int reg=0;reg<4;reg++){
        int row=wv*16+q4*4+reg;
        xis2[lm*149+row]=xa[reg]+b_ifL[row];
      }
      if(wv==0){
        f32x4 xb=(f32x4){0.f,0.f,0.f,0.f};
        #pragma unroll
        for(int hh=0;hh<4;hh++){
          uint4 w4[4];
          #pragma unroll
          for(int cc=0;cc<4;cc++) w4[cc]=PWv[(128+hh*4+cc)*64+l];
          #pragma unroll
          for(int cc=0;cc<4;cc++){
            U4H8 t4; t4.u=w4[cc];
            f16x8 bfr=HBv[1024+((hh*4+cc)*4+q4)*16+lm];
            xb=__builtin_amdgcn_mfma_f32_16x16x32_f16(t4.h,bfr,xb,0,0,0);
          }
        }
        #pragma unroll
        for(int reg=0;reg<4;reg++){
          int row=128+q4*4+reg;
          xis2[lm*149+row]=xb[reg]+b_ifL[row];
        }
      }
    }
    __syncthreads();

    // ====== DNC machinery: wave-local per batch (half-wave = 32 lanes) ======
    // M1
    if(mu<5){
      int m=mu;
      float u=s_usage[mb*5+m]+(1.f-s_usage[mb*5+m])*s_wwp[mb*5+m];
      float psi=1.f;
      #pragma unroll
      for(int rr=0;rr<4;rr++) psi *= 1.f - sigf(XI(117+rr))*s_rwp[mb*20+rr*5+m];
      u*=psi; s_usage[mb*5+m]=u;
      float nm=0.f,dt=0.f,nk=0.f;
      #pragma unroll
      for(int w=0;w<16;w++){
        float mv=s_mem[mb*80+m*16+w], kv=tanhf(XI(68+w));
        nm+=mv*mv; dt+=mv*kv; nk+=kv*kv;
      }
      float sim=dt/((sqrtf(nm)+1e-6f)*(sqrtf(nk)+1e-6f));
      s_wl[mb*5+m]=sim*splus(XI(84));
    }
    WB();
    // M2 (parallel, 5 lanes/batch; stable-rank allocation)
    if(mu<5){
      int m=mu;
      float mx=s_wl[mb*5];
      #pragma unroll
      for(int j=1;j<5;j++) mx=fmaxf(mx,s_wl[mb*5+j]);
      float e=expf(s_wl[mb*5+m]-mx);
      float u=1e-6f+(1.f-1e-6f)*s_usage[mb*5+m];
      s_rl [mb*20+m]=u;   // scratch (overwritten by M4)
      s_bwd[mb*20+m]=e;   // scratch (overwritten by M4)
    }
    WB();
    if(mu<5){
      int m=mu;
      float u=s_rl[mb*20+m], e=s_bwd[mb*20+m];
      float s=0.f, prod=1.f;
      #pragma unroll
      for(int j=0;j<5;j++){
        s+=s_bwd[mb*20+j];
        float uj=s_rl[mb*20+j];
        if(uj<u || (uj==u && j<m)) prod*=uj;
      }
      float wcw=e/s;
      float alloc=(1.f-u)*prod;
      float ag=sigf(XI(121)), wgg=sigf(XI(122));
      float w_=wgg*(ag*alloc+(1.f-ag)*wcw);
      s_ww[mb*5+m]=w_;
    }
    WB();
    if(mu==0){
      float ws=0.f;
      #pragma unroll
      for(int m=0;m<5;m++) ws+=s_ww[mb*5+m];
      s_wsum[mb]=ws;
    }
    WB();
    // M3
    for(int k=mu;k<80;k+=32){
      int m=k>>4,w=k&15;
      float er=sigf(XI(85+w)), wv2=tanhf(XI(101+w));
      float w_=s_ww[mb*5+m];
      s_mem2[mb*80+k]=s_mem[mb*80+k]*(1.f-w_*er)+w_*wv2;
    }
    if(mu<25){
      int i=mu/5, j=mu-5*i;
      s_link2[mb*25+mu]=(i==j)?0.f:((1.f-s_ww[mb*5+i]-s_ww[mb*5+j])*s_link[mb*25+mu]+s_ww[mb*5+i]*s_prec[mb*5+j]);
    } else if(mu<30){
      int j=mu-25;
      s_prec2[mb*5+j]=(1.f-s_wsum[mb])*s_prec[mb*5+j]+s_ww[mb*5+j];
    }
    WB();
    // M4
    if(mu<20){
      int rr=mu/5, m=mu-5*rr;
      float nm=0.f,dt=0.f,nk=0.f;
      #pragma unroll
      for(int w=0;w<16;w++){
        float mv=s_mem2[mb*80+m*16+w], kv=tanhf(XI(rr*16+w));
        nm+=mv*mv; dt+=mv*kv; nk+=kv*kv;
      }
      float sim=dt/((sqrtf(nm)+1e-6f)*(sqrtf(nk)+1e-6f));
      s_rl[mb*20+mu]=sim*splus(XI(64+rr));
      float af=0.f, ab=0.f;
      #pragma unroll
      for(int j=0;j<5;j++) af+=s_link2[mb*25+m*5+j]*s_rwp[mb*20+rr*5+j];
      #pragma unroll
      for(int i=0;i<5;i++) ab+=s_link2[mb*25+i*5+m]*s_rwp[mb*20+rr*5+i];
      s_fwd[mb*20+rr*5+m]=af;
      s_bwd[mb*20+rr*5+m]=ab;
    }
    WB();
    // M5
    if(mu<20){
      int rr=mu/5;
      float mx=-1e30f;
      #pragma unroll
      for(int m=0;m<5;m++) mx=fmaxf(mx,s_rl[mb*20+rr*5+m]);
      float s=0.f;
      #pragma unroll
      for(int m=0;m<5;m++) s+=expf(s_rl[mb*20+rr*5+m]-mx);
      float rcw=expf(s_rl[mb*20+mu]-mx)/s;
      float q0=XI(123+3*rr),q1=XI(124+3*rr),q2=XI(125+3*rr);
      float m3=fmaxf(q0,fmaxf(q1,q2));
      float e0=expf(q0-m3),e1=expf(q1-m3),e2=expf(q2-m3);
      float inv=1.f/(e0+e1+e2);
      s_rw[mb*20+mu]=(e0*s_bwd[mb*20+mu]+e1*s_fwd[mb*20+mu]+e2*rcw)*inv;
    }
    WB();
    // M6
    for(int k=mu;k<64;k+=32){
      int rr=k>>4,w=k&15;
      float a=0.f;
      #pragma unroll
      for(int m=0;m<5;m++) a+=s_rw[mb*20+rr*5+m]*s_mem2[mb*80+m*16+w];
      rvbuf[mb*64+k]=a;
    }
    for(int k=mu;k<80;k+=32) s_mem[mb*80+k]=s_mem2[mb*80+k];
    if(mu<25) s_link[mb*25+mu]=s_link2[mb*25+mu];
    else if(mu<30) s_prec[mb*5+mu-25]=s_prec2[mb*5+mu-25];
    if(mu<20) s_rwp[mb*20+mu]=s_rw[mb*20+mu];
    if(mu>=27&&mu<32){ int m=mu-27; s_wwp[mb*5+m]=s_ww[mb*5+m]; }
    __syncthreads();

    if(tt==511){
      int cb=((g*16+r)*512+tt)*576;
      if(tid<128){
        int kg=tid>>1, e=tid&1;
        U64H4 pv; pv.u=HB[2048+(kg*16+r)*2+e];
        #pragma unroll
        for(int i=0;i<4;i++){
          float x=(float)pv.h[i];
          cat[cb+kg*8+e*4+i]=__float2bfloat16(fminf(fmaxf(x,-20.f),20.f));
        }
      }
      if(tid<64) cat[cb+512+tid]=__float2bfloat16(rvbuf[r*64+tid]);
      break;
    }

    // build lr B-frags in HB[4096..4351]
    if(tid<256){
      int kg=tid>>5, rem=tid&31, b2=rem>>1, e=rem&1;
      U64H4 pk;
      #pragma unroll
      for(int i=0;i<4;i++) pk.h[i]=(f16)rvbuf[b2*64 + kg*8+e*4+i];
      HB[4096+(kg*16+b2)*2+e]=pk.u;
    }
    __syncthreads();
    // A(tt+1) p2: lr chunks (prefetched weights)
    #pragma unroll
    for(int c2=0;c2<2;c2++){
      U4H8 wf; wf.u=pfA2[c2];
      f16x8 bfr=HBv[2048+(c2*4+q4)*16+lm];
      accA=__builtin_amdgcn_mfma_f32_16x16x32_f16(wf.h,bfr,accA,0,0,0);
    }
    #pragma unroll
    for(int reg=0;reg<4;reg++) PR[(wv*16+q4*4+reg)*17+lm]=accA[reg];
    __syncthreads();
    {
      float gi=PR[(d    )*17+bb]+em0;
      float gf=PR[(32+d )*17+bb]+em1;
      float gg=PR[(64+d )*17+bb]+em2;
      float go=PR[(96+d )*17+bb]+em3;
      float c0=sigf(gf)*c0s+sigf(gi)*tanhf(gg);
      c0s=c0;
      float h=sigf(go)*tanhf(c0);
      sh_pub[d*16+bb]=(f16)h;
    }
    __syncthreads();
    if(tid<128){
      int ks=tid>>4, b2=tid&15;
      U64H4 pk;
      #pragma unroll
      for(int i=0;i<4;i++) pk.h[i]=sh_pub[(ks*4+i)*16+b2];
      ast64(&GX0[g*4096+pn*2048+((4*r+(ks>>1))*16+b2)*2+(ks&1)], pk.u);
    }
    PUBF(2*tt+4);      // alpha(tt+1)

    // cover2: B(tt+1) p1 on h1(tt) in HB; cat stores; prefetch B-low frags
    f32x4 accB=(f32x4){0.f,0.f,0.f,0.f};
    #pragma unroll
    for(int c=16;c<32;c++){
      U4H8 wf; wf.u=PBv[((r*8+wv)*32+c)*64+l];
      f16x8 bfr=HBv[1024+((c-16)*4+q4)*16+lm];
      accB=__builtin_amdgcn_mfma_f32_16x16x32_f16(wf.h,bfr,accB,0,0,0);
    }
    uint4 pfB[16];
    #pragma unroll
    for(int c=0;c<16;c++) pfB[c]=PBv[((r*8+wv)*32+c)*64+l];
    {
      int cb=((g*16+r)*512+tt)*576;
      if(tid<128){
        int kg=tid>>1, e=tid&1;
        U64H4 pv; pv.u=HB[2048+(kg*16+r)*2+e];
        #pragma unroll
        for(int i=0;i<4;i++){
          float x=(float)pv.h[i];
          cat[cb+kg*8+e*4+i]=__float2bfloat16(fminf(fmaxf(x,-20.f),20.f));
        }
      }
      if(tid<64) cat[cb+512+tid]=__float2bfloat16(rvbuf[r*64+tid]);
    }

    WAITG(2*tt+4);     // alpha(tt+1)

    // B(tt+1) p2: stage h0(tt+1) (also next cover1 operand), MFMA, nonlin1
    {
      u64 s0=ald64(&GX0[g*4096+pn*2048+tid      ]);
      u64 s1=ald64(&GX0[g*4096+pn*2048+tid+512  ]);
      u64 s2=ald64(&GX0[g*4096+pn*2048+tid+1024 ]);
      u64 s3=ald64(&GX0[g*4096+pn*2048+tid+1536 ]);
      HB[tid]=s0; HB[tid+512]=s1; HB[tid+1024]=s2; HB[tid+1536]=s3;
    }
    __syncthreads();
    #pragma unroll
    for(int c=0;c<16;c++){
      U4H8 wf; wf.u=pfB[c];
      f16x8 bfr=HBv[(c*4+q4)*16+lm];
      accB=__builtin_amdgcn_mfma_f32_16x16x32_f16(wf.h,bfr,accB,0,0,0);
    }
    #pragma unroll
    for(int reg=0;reg<4;reg++) PR[(wv*16+q4*4+reg)*17+lm]=accB[reg];
    __syncthreads();
    {
      float gi=PR[(d    )*17+bb]+sh_b1[d];
      float gf=PR[(32+d )*17+bb]+sh_b1[32+d];
      float gg=PR[(64+d )*17+bb]+sh_b1[64+d];
      float go=PR[(96+d )*17+bb]+sh_b1[96+d];
      float c1=sigf(gf)*c1s+sigf(gi)*tanhf(gg);
      c1s=c1;
      float h=sigf(go)*tanhf(c1);
      sh_pub[d*16+bb]=(f16)h;
    }
    __syncthreads();
    if(tid<128){
      int ks=tid>>4, b2=tid&15;
      U64H4 pk;
      #pragma unroll
      for(int i=0;i<4;i++) pk.h[i]=sh_pub[(ks*4+i)*16+b2];
      ast64(&GX1[g*4096+pn*2048+((4*r+(ks>>1))*16+b2)*2+(ks&1)], pk.u);
    }
    PUBF(2*tt+5);      // beta(tt+1)
  }
#undef WAITG
#undef PUBF
#undef XI
#undef WB
}

// ---------------- final output GEMM (f32 out) ----------------
__global__ void __launch_bounds__(256) k_out(const bf16* __restrict__ cat,
                                             const float* __restrict__ Wc,
                                             const float* __restrict__ bc,
                                             float* __restrict__ outp){
  int t0=blockIdx.x*64, v0=blockIdx.y*64, b=blockIdx.z;
  __shared__ float As[64][33];
  __shared__ float Bs[32][65];
  int tid=threadIdx.x;
  int ti=tid>>4, vi=tid&15;
  float acc[4][4]={};
  for(int k0=0;k0<576;k0+=32){
    for(int i=tid;i<64*32;i+=256){
      int rr=i>>5,k=i&31;
      As[rr][k]=b2f(cat[(b*512+t0+rr)*576+k0+k]);
    }
    for(int i=tid;i<64*32;i+=256){
      int v=i>>5,k=i&31;
      Bs[k][v]=Wc[(v0+v)*576+k0+k];
    }
    __syncthreads();
    #pragma unroll 8
    for(int kk=0;kk<32;kk++){
      float av[4],bv[4];
      #pragma unroll
      for(int x=0;x<4;x++) av[x]=As[ti*4+x][kk];
      #pragma unroll
      for(int y=0;y<4;y++) bv[y]=Bs[kk][vi*4+y];
      #pragma unroll
      for(int x=0;x<4;x++)
        #pragma unroll
        for(int y=0;y<4;y++) acc[x][y]+=av[x]*bv[y];
    }
    __syncthreads();
  }
  #pragma unroll
  for(int y=0;y<4;y++){
    int v=v0+vi*4+y;
    float bcv=bc[v];
    #pragma unroll
    for(int x=0;x<4;x++){
      int tt=t0+ti*4+x;
      outp[(b*256+v)*512+tt]=acc[x][y]+bcv;
    }
  }
}

extern "C" void kernel_launch(void* const* d_in, const int* in_sizes, int n_in,
                              void* d_out, int out_size, void* d_ws, size_t ws_size,
                              hipStream_t stream) {
  const int*  tokens = (const int*) d_in[0];
  const void* emb    = d_in[1];
  const void* Wi0    = d_in[2];
  const void* Wh0    = d_in[3];
  const void* b0     = d_in[4];
  const void* Wi1    = d_in[5];
  const void* Wh1    = d_in[6];
  const void* b1     = d_in[7];
  const void* W_if   = d_in[8];
  const void* b_if   = d_in[9];
  const void* W_out  = d_in[10];
  const void* b_out  = d_in[11];
  const void* W_fc   = d_in[12];
  const void* b_fc   = d_in[13];

  static const int expect[14] = {64*512, 256*512, 2048*576, 2048*512, 2048,
                                 2048*512, 2048*512, 2048, 135*512, 135,
                                 512*576, 512, 256*512, 256};
  bool ok = (n_in == 14);
  if(ok) for(int i=0;i<14;i++) if(in_sizes[i]!=expect[i]) ok=false;

  int*      flags = (int*)d_ws;                   // [0]=dtype flag
  float*    embW  = (float*)d_ws + 64;            // 2048*256
  ushort_t* PA    = (ushort_t*)(embW + 524288);   // 1179648 f16 used (region 1310720; FL at +1179648)
  ushort_t* PB    = PA + 1310720;                 // 2097152 f16
  float*    Wreg  = (float*)(PB + 2097152);       // PW (73728 f16) lives here
  float*    b_ifF = Wreg + 69632;                 // 160
  float*    Wc    = b_ifF + 160;                  // 147456
  float*    bc    = Wc + 147456;                  // 256
  u64*      GX0   = (u64*)(bc + 256);             // 16384 u64 = [4 grp][2 ph][2048]
  u64*      GX1   = GX0 + 16384;                  // 16384 u64
  u64*      GXL   = GX1 + 16384;                  // 2048 u64 (unused, layout keep)
  bf16*     cat   = (bf16*)(GXL + 2048);          // 64*512*576
  unsigned* FL    = (unsigned*)(PA + 1179648);    // 64 dwords: 4 groups x 16 flags
  ushort_t* PW    = (ushort_t*)Wreg;              // 73728 f16

  size_t need = 9783168ull + 278528ull + 37748736ull;   // = 47,810,432 B
  if(!ok || ws_size < need){
    hipMemsetAsync(d_out, 0, (size_t)out_size*4, stream);
    return;
  }

  k_detect<<<dim3(1), dim3(256), 0, stream>>>(emb, flags);
  k_embW<<<dim3(2048), dim3(256), 0, stream>>>(emb, Wi0, b0, flags, embW);
  k_wpkA<<<dim3(4608), dim3(256), 0, stream>>>(Wh0, Wi0, flags, PA);
  k_wpkB<<<dim3(8192), dim3(256), 0, stream>>>(Wi1, Wh1, flags, PB);
  k_wifP<<<dim3(288), dim3(256), 0, stream>>>(W_if, b_if, flags, PW, b_ifF, FL);
  k_wc  <<<dim3(576),  dim3(256), 0, stream>>>(W_fc, W_out, b_out, b_fc, flags, Wc, bc);

  void* kargs[] = {
    (void*)&tokens, (void*)&b1, (void*)&flags,
    (void*)&embW, (void*)&PA, (void*)&PB,
    (void*)&PW, (void*)&b_ifF,
    (void*)&GX0, (void*)&GX1, (void*)&FL,
    (void*)&cat
  };
  hipLaunchCooperativeKernel((const void*)k_dnc3, dim3(64), dim3(512), kargs, 0, stream);

  k_out<<<dim3(8,4,64), dim3(256), 0, stream>>>(cat, Wc, bc, (float*)d_out);
}

// Round 8
// 12075.298 us; speedup vs baseline: 6.3371x; 1.0356x over previous
//
#include <hip/hip_runtime.h>
#include <hip/hip_bf16.h>

typedef __hip_bfloat16 bf16;
typedef _Float16 f16;
typedef _Float16 f16x8 __attribute__((ext_vector_type(8)));
typedef float f32x4 __attribute__((ext_vector_type(4)));
typedef unsigned long long u64;
typedef unsigned short ushort_t;

__device__ __forceinline__ float b2f(bf16 x){ return __bfloat162float(x); }
__device__ __forceinline__ float sigf(float x){ return 1.f/(1.f+expf(-x)); }
__device__ __forceinline__ float splus(float x){ return fmaxf(x,0.f)+log1pf(expf(-fabsf(x))); }
__device__ __forceinline__ float ldf(const void* p, int i, int isf32){
  return isf32 ? ((const float*)p)[i] : __bfloat162float(((const bf16*)p)[i]);
}
// agent-scope coherent ops (bypass per-XCD L2). Proven cross-XCD coherent, no fences.
__device__ __forceinline__ void ast64(u64* p, u64 v){ __hip_atomic_store(p, v, __ATOMIC_RELAXED, __HIP_MEMORY_SCOPE_AGENT); }
__device__ __forceinline__ u64 ald64(u64* p){ return __hip_atomic_load(p, __ATOMIC_RELAXED, __HIP_MEMORY_SCOPE_AGENT); }
__device__ __forceinline__ void ast32(unsigned* p, unsigned v){ __hip_atomic_store(p, v, __ATOMIC_RELAXED, __HIP_MEMORY_SCOPE_AGENT); }
__device__ __forceinline__ unsigned ald32(unsigned* p){ return __hip_atomic_load(p, __ATOMIC_RELAXED, __HIP_MEMORY_SCOPE_AGENT); }

union U4H8 { uint4 u; f16x8 h; };
union U64H4 { u64 u; f16 h[4]; };
union H16 { f16 h; ushort_t s; };

// ---------------- dtype detect ----------------
__global__ void k_detect(const void* __restrict__ emb, int* __restrict__ flag){
  __shared__ float mx[256];
  int tid=threadIdx.x;
  float v = fabsf(__bfloat162float(((const bf16*)emb)[tid]));
  mx[tid]=v; __syncthreads();
  for(int s=128;s>0;s>>=1){ if(tid<s) mx[tid]=fmaxf(mx[tid],mx[tid+s]); __syncthreads(); }
  if(tid==0){ flag[0] = (mx[0]>1000.f) ? 1 : 0; flag[1] = 0; }
}

// ---------------- setup ----------------
// embW[row][v] = b0[row] + sum_k emb[v][k]*Wi0[row][k]   (row-major [2048][256])
__global__ void k_embW(const void* __restrict__ emb, const void* __restrict__ Wi0,
                       const void* __restrict__ b0,
                       const int* __restrict__ flags, float* __restrict__ embW){
  int f=flags[0];
  int row = blockIdx.x;
  __shared__ float w[512];
  for(int k=threadIdx.x;k<512;k+=256) w[k]=ldf(Wi0,row*576+k,f);
  __syncthreads();
  int v = threadIdx.x;
  float acc=ldf(b0,row,f);
  #pragma unroll 4
  for(int k=0;k<512;k++) acc += ldf(emb,v*512+k,f)*w[k];
  embW[row*256+v]=acc;
}

// ---- layer-0 sliced prepack, TRANSPOSED rows (row-in-tile = dd*4+G) so one
// f32x4 acc holds all 4 gates of one dim (register-local nonlinearity).
// Block r, wave w owns dims r*32+w*4+[0,4). PA[(((r*8+w)*18+c)*64+l)*8+j]:
// tr=l&15 -> G=tr&3, dd=tr>>2; row=G*512+r*32+w*4+dd; k=c*32+(l>>4)*8+j;
// k<512 -> Wh0, k>=512 -> Wi0 lr cols.
__global__ void k_wpkA(const void* __restrict__ Wh0, const void* __restrict__ Wi0,
                       const int* __restrict__ flags, ushort_t* __restrict__ PA){
  int f=flags[0];
  int idx=blockIdx.x*256+threadIdx.x;
  if(idx>=1179648) return;
  int j=idx&7, l=(idx>>3)&63, rest=idx>>9;
  int c=rest%18, t2=rest/18, w=t2&7, r=t2>>3;
  int tr=l&15, q4=l>>4;
  int G=tr&3, dd=tr>>2;
  int row=G*512 + r*32 + w*4 + dd;
  int k=c*32 + q4*8 + j;
  float val = (k<512)? ldf(Wh0,row*512+k,f) : ldf(Wi0,row*576+k,f);
  H16 hx; hx.h=(f16)val; PA[idx]=hx.s;
}
// ---- layer-1 sliced prepack, transposed (ROUND-6 verified code, lifted) ----
// PB[(((r*8+w)*32+c)*64+l)*8+j]: row=G*512+r*32+w*4+dd; k<512 Wi1 (h0), else Wh1.
__global__ void k_wpkB(const void* __restrict__ Wi1, const void* __restrict__ Wh1,
                       const int* __restrict__ flags, ushort_t* __restrict__ PB){
  int f=flags[0];
  int idx=blockIdx.x*256+threadIdx.x;
  if(idx>=2097152) return;
  int j=idx&7, l=(idx>>3)&63, rest=idx>>9;
  int c=rest&31, t2=rest>>5, w=t2&7, r=t2>>3;
  int tr=l&15, q4=l>>4;
  int G=tr&3, dd=tr>>2;
  int row=G*512 + r*32 + w*4 + dd;
  int k=c*32 + q4*8 + j;
  float val = (k<512)? ldf(Wi1,row*512+k,f) : ldf(Wh1,row*512+k-512,f);
  H16 hx; hx.h=(f16)val; PB[idx]=hx.s;
}

// W_if prepack into MFMA A-frags: 9 tiles of 16 rows (135..143 zero-padded),
// 16 K-chunks. PW[((tile*16+c)*64+l)*8+j]. Also zeroes FL, loads b_ifF.
__global__ void k_wifP(const void* __restrict__ W_if, const void* __restrict__ b_if,
                       const int* __restrict__ flags,
                       ushort_t* __restrict__ PW, float* __restrict__ b_ifF,
                       unsigned* __restrict__ FLz){
  int f=flags[0];
  int idx=blockIdx.x*256+threadIdx.x;
  if(idx<73728){
    int j=idx&7, l=(idx>>3)&63, c=(idx>>9)&15, tile=idx>>13;
    int row=tile*16+(l&15);
    int k=c*32+(l>>4)*8+j;
    float val=(row<135)? ldf(W_if,row*512+k,f) : 0.f;
    H16 hx; hx.h=(f16)val; PW[idx]=hx.s;
  }
  if(idx<64) FLz[idx]=0u;
  if(idx<135) b_ifF[idx]=ldf(b_if,idx,f);
}

__global__ void k_wc(const void* __restrict__ W_fc, const void* __restrict__ W_out,
                     const void* __restrict__ b_out, const void* __restrict__ b_fc,
                     const int* __restrict__ flags,
                     float* __restrict__ Wc, float* __restrict__ bc){
  int f=flags[0];
  int idx=blockIdx.x*256+threadIdx.x;
  int v=idx/576, j=idx-v*576;
  float acc=0.f;
  #pragma unroll 4
  for(int d=0;d<512;d++) acc += ldf(W_fc,v*512+d,f)*ldf(W_out,d*576+j,f);
  Wc[idx]=acc;
  if(j==0){
    float a=ldf(b_fc,v,f);
    for(int d=0;d<512;d++) a += ldf(W_fc,v*512+d,f)*ldf(b_out,d,f);
    bc[v]=a;
  }
}

// ---------------- grouped recurrence (2-hop) + register-local nonlins ----------------
// 4 groups x 16 blocks; block (g,r) owns dims [32r,32r+32); L2-resident slices.
// P3 machinery redundant per block; xi via MFMA vs staged h1.
// NEW vs round 7: (1) transposed gate-grouped PA/PB -> one acc = 4 gates of one
// dim -> nonlinearities register-local, PR exchange eliminated (4 syncthreads +
// bank-conflict source gone); (2) machinery transcendental precompute into
// s_pre[batch][112] (tanh/sig of keys/erase/write computed once, not 4-5x).
// Flags: FL[g*16+r] monotone: init=1, alpha(t)=2t+2, beta(t)=2t+3.
__attribute__((amdgpu_waves_per_eu(2,2)))
__global__ void __launch_bounds__(512) k_dnc3(
    const int* __restrict__ tokens, const void* __restrict__ b1, const int* __restrict__ flags,
    const float* __restrict__ embW, const ushort_t* __restrict__ PA, const ushort_t* __restrict__ PB,
    const ushort_t* __restrict__ PW, const float* __restrict__ b_ifF,
    u64* GX0, u64* GX1, unsigned* FL,
    bf16* __restrict__ cat)
{
  const int bid = blockIdx.x;
  const int g   = bid>>4, r = bid&15;
  const int tid = threadIdx.x;
  const int wv  = tid>>6, l = tid&63;
  const int lm  = l&15,  q4 = l>>4;
  const int mb  = tid>>5, mu = tid&31;     // machinery mapping (batch, slot)
  const int f32i = flags[0];

  __shared__ __align__(16) u64 HB[4352];   // [0..2047] h0 | [2048..4095] h1 | [4096..4351] lr frags
  __shared__ f16  sh_pub[512];
  __shared__ int  tokL[16];
  __shared__ float b_ifL[144];
  __shared__ float xis2[16*149];
  __shared__ float s_pre[16*112];          // precomputed transcendentals per batch
  __shared__ float s_mem[1280], s_mem2[1280], s_link[400], s_link2[400];
  __shared__ float s_prec[80], s_prec2[80], s_rwp[320], s_rw[320];
  __shared__ float s_wwp[80], s_ww[80], s_usage[80], s_wl[80];
  __shared__ float s_rl[320], s_fwd[320], s_bwd[320], s_wsum[16];
  __shared__ float rvbuf[1024];

#define WAITG(TGT) do{ if(tid<16){ unsigned _tg=(unsigned)(TGT); int _wd=0; \
    while(ald32(&FL[g*16+tid]) < _tg && _wd<50000000){ __builtin_amdgcn_s_sleep(1); _wd++; } } \
  __syncthreads(); }while(0)
#define PUBF(VAL) do{ __syncthreads(); \
  if(tid==0) ast32(&FL[g*16+r],(unsigned)(VAL)); }while(0)
#define XI(i) xis2[mb*149+(i)]
#define WB() __builtin_amdgcn_wave_barrier()

  const f16x8* HBv=(const f16x8*)HB;
  const uint4* PAv=(const uint4*)PA;
  const uint4* PBv=(const uint4*)PB;
  const uint4* PWv=(const uint4*)PW;

  // per-thread biases for (dim1 = r*32+wv*4+q4), 4 gates (round-6 verified)
  const int dim1 = r*32 + wv*4 + q4;
  const float b1Li=ldf(b1,dim1,f32i), b1Lf=ldf(b1,512+dim1,f32i),
              b1Lg=ldf(b1,1024+dim1,f32i), b1Lo=ldf(b1,1536+dim1,f32i);

  if(tid<144) b_ifL[tid]=(tid<135)? b_ifF[tid] : 0.f;
  for(int i=tid;i<1280;i+=512) s_mem[i]=0.f;
  for(int i=tid;i<400;i+=512) s_link[i]=0.f;
  for(int i=tid;i<320;i+=512) s_rwp[i]=0.f;
  if(tid<80){ s_prec[tid]=0.f; s_wwp[tid]=0.f; s_usage[tid]=0.f; }
  float c0s=0.f, c1s=0.f;

  // ---- prologue t=0: h0(0)=f(em(0)); h1(0)=g(h0(0)) ----
  if(tid<16) tokL[tid]=tokens[(g*16+tid)*512];
  __syncthreads();
  {
    int tok=tokL[lm];
    float ei=embW[dim1*256+tok];
    float eg=embW[262144+dim1*256+tok];
    float eo=embW[393216+dim1*256+tok];
    c0s = sigf(ei)*tanhf(eg);
    sh_pub[(wv*4+q4)*16+lm]=(f16)(sigf(eo)*tanhf(c0s));
  }
  __syncthreads();
  if(tid<128){
    int ks=tid>>4, b2=tid&15;
    U64H4 pk;
    #pragma unroll
    for(int i=0;i<4;i++) pk.h[i]=sh_pub[(ks*4+i)*16+b2];
    ast64(&GX0[g*4096+((4*r+(ks>>1))*16+b2)*2+(ks&1)], pk.u);
  }
  PUBF(2u);            // alpha(0)
  WAITG(2u);
  {
    u64 s0=ald64(&GX0[g*4096+tid      ]);
    u64 s1=ald64(&GX0[g*4096+tid+512  ]);
    u64 s2=ald64(&GX0[g*4096+tid+1024 ]);
    u64 s3=ald64(&GX0[g*4096+tid+1536 ]);
    HB[tid]=s0; HB[tid+512]=s1; HB[tid+1024]=s2; HB[tid+1536]=s3;
  }
  __syncthreads();
  {
    f32x4 acc1=(f32x4){0.f,0.f,0.f,0.f};
    #pragma unroll
    for(int c=0;c<16;c++){
      U4H8 wf; wf.u=PBv[((r*8+wv)*32+c)*64+l];
      f16x8 bfr=HBv[(c*4+q4)*16+lm];
      acc1=__builtin_amdgcn_mfma_f32_16x16x32_f16(wf.h,bfr,acc1,0,0,0);
    }
    float gi=acc1[0]+b1Li, gg=acc1[2]+b1Lg, go=acc1[3]+b1Lo;
    c1s=sigf(gi)*tanhf(gg);
    sh_pub[(wv*4+q4)*16+lm]=(f16)(sigf(go)*tanhf(c1s));
  }
  __syncthreads();
  if(tid<128){
    int ks=tid>>4, b2=tid&15;
    U64H4 pk;
    #pragma unroll
    for(int i=0;i<4;i++) pk.h[i]=sh_pub[(ks*4+i)*16+b2];
    ast64(&GX1[g*4096+((4*r+(ks>>1))*16+b2)*2+(ks&1)], pk.u);
  }
  PUBF(3u);            // beta(0)

  // ---- main loop ----
  for(int tt=0;tt<512;tt++){
    const int p=tt&1, pn=p^1;

    // cover1: A p1 (16 chunks) on h0(tt) resident in HB[0..2047]
    f32x4 accA=(f32x4){0.f,0.f,0.f,0.f};
    #pragma unroll
    for(int c=0;c<16;c++){
      U4H8 wf; wf.u=PAv[((r*8+wv)*18+c)*64+l];
      f16x8 bfr=HBv[(c*4+q4)*16+lm];
      accA=__builtin_amdgcn_mfma_f32_16x16x32_f16(wf.h,bfr,accA,0,0,0);
    }
    // prefetch em(tt+1) and A2 lr-frag weights (independent of the hop)
    float em0,em1,em2,em3;
    {
      int tn=(tt<511)?tt+1:511;
      int tok=tokens[(g*16+lm)*512+tn];
      em0=embW[dim1*256+tok]; em1=embW[131072+dim1*256+tok];
      em2=embW[262144+dim1*256+tok]; em3=embW[393216+dim1*256+tok];
    }
    uint4 pfA2[2];
    #pragma unroll
    for(int c2=0;c2<2;c2++) pfA2[c2]=PAv[((r*8+wv)*18+16+c2)*64+l];

    WAITG(2*tt+3);     // beta(tt)

    // stage h1(tt) -> HB[2048..4095]
    {
      u64 s0=ald64(&GX1[g*4096+p*2048+tid      ]);
      u64 s1=ald64(&GX1[g*4096+p*2048+tid+512  ]);
      u64 s2=ald64(&GX1[g*4096+p*2048+tid+1024 ]);
      u64 s3=ald64(&GX1[g*4096+p*2048+tid+1536 ]);
      HB[2048+tid]=s0; HB[2048+tid+512]=s1; HB[2048+tid+1024]=s2; HB[2048+tid+1536]=s3;
    }
    __syncthreads();

    // ====== P3(tt): xi = W_if @ h1 via MFMA (redundant per block) ======
    {
      f32x4 xa=(f32x4){0.f,0.f,0.f,0.f};
      #pragma unroll
      for(int hh=0;hh<4;hh++){
        uint4 w4[4];
        #pragma unroll
        for(int cc=0;cc<4;cc++) w4[cc]=PWv[(wv*16+hh*4+cc)*64+l];
        #pragma unroll
        for(int cc=0;cc<4;cc++){
          U4H8 t4; t4.u=w4[cc];
          f16x8 bfr=HBv[1024+((hh*4+cc)*4+q4)*16+lm];
          xa=__builtin_amdgcn_mfma_f32_16x16x32_f16(t4.h,bfr,xa,0,0,0);
        }
      }
      #pragma unroll
      for(int reg=0;reg<4;reg++){
        int row=wv*16+q4*4+reg;
        xis2[lm*149+row]=xa[reg]+b_ifL[row];
      }
      if(wv==0){
        f32x4 xb=(f32x4){0.f,0.f,0.f,0.f};
        #pragma unroll
        for(int hh=0;hh<4;hh++){
          uint4 w4[4];
          #pragma unroll
          for(int cc=0;cc<4;cc++) w4[cc]=PWv[(128+hh*4+cc)*64+l];
          #pragma unroll
          for(int cc=0;cc<4;cc++){
            U4H8 t4; t4.u=w4[cc];
            f16x8 bfr=HBv[1024+((hh*4+cc)*4+q4)*16+lm];
            xb=__builtin_amdgcn_mfma_f32_16x16x32_f16(t4.h,bfr,xb,0,0,0);
          }
        }
        #pragma unroll
        for(int reg=0;reg<4;reg++){
          int row=128+q4*4+reg;
          xis2[lm*149+row]=xb[reg]+b_ifL[row];
        }
      }
    }
    __syncthreads();

    // ====== machinery (wave-local per batch, half-wave = 32 lanes) ======
    // PRE: transcendentals once per batch: [0..15] tanh(wkey) [16..31] sig(erase)
    // [32..47] tanh(wvec) [48..111] tanh(rkey[rr][w])
    if(mu<16){
      s_pre[mb*112+mu]    =tanhf(XI(68+mu));
      s_pre[mb*112+16+mu] =sigf (XI(85+mu));
      s_pre[mb*112+32+mu] =tanhf(XI(101+mu));
    }
    s_pre[mb*112+48+mu]   =tanhf(XI(mu));
    s_pre[mb*112+48+32+mu]=tanhf(XI(32+mu));
    WB();
    // M1
    if(mu<5){
      int m=mu;
      float u=s_usage[mb*5+m]+(1.f-s_usage[mb*5+m])*s_wwp[mb*5+m];
      float psi=1.f;
      #pragma unroll
      for(int rr=0;rr<4;rr++) psi *= 1.f - sigf(XI(117+rr))*s_rwp[mb*20+rr*5+m];
      u*=psi; s_usage[mb*5+m]=u;
      float nm=0.f,dt=0.f,nk=0.f;
      #pragma unroll
      for(int w=0;w<16;w++){
        float mv=s_mem[mb*80+m*16+w], kv=s_pre[mb*112+w];
        nm+=mv*mv; dt+=mv*kv; nk+=kv*kv;
      }
      float sim=dt/((sqrtf(nm)+1e-6f)*(sqrtf(nk)+1e-6f));
      s_wl[mb*5+m]=sim*splus(XI(84));
    }
    WB();
    // M2a
    if(mu<5){
      int m=mu;
      float mx=s_wl[mb*5];
      #pragma unroll
      for(int j=1;j<5;j++) mx=fmaxf(mx,s_wl[mb*5+j]);
      float e=expf(s_wl[mb*5+m]-mx);
      float u=1e-6f+(1.f-1e-6f)*s_usage[mb*5+m];
      s_rl [mb*20+m]=u;   // scratch (overwritten by M4)
      s_bwd[mb*20+m]=e;   // scratch (overwritten by M4)
    }
    WB();
    // M2b: stable-rank allocation
    if(mu<5){
      int m=mu;
      float u=s_rl[mb*20+m], e=s_bwd[mb*20+m];
      float s=0.f, prod=1.f;
      #pragma unroll
      for(int j=0;j<5;j++){
        s+=s_bwd[mb*20+j];
        float uj=s_rl[mb*20+j];
        if(uj<u || (uj==u && j<m)) prod*=uj;
      }
      float wcw=e/s;
      float alloc=(1.f-u)*prod;
      float ag=sigf(XI(121)), wgg=sigf(XI(122));
      s_ww[mb*5+m]=wgg*(ag*alloc+(1.f-ag)*wcw);
    }
    WB();
    if(mu==0){
      float ws=0.f;
      #pragma unroll
      for(int m=0;m<5;m++) ws+=s_ww[mb*5+m];
      s_wsum[mb]=ws;
    }
    WB();
    // M3
    for(int k=mu;k<80;k+=32){
      int m=k>>4,w=k&15;
      float er=s_pre[mb*112+16+w], wv2=s_pre[mb*112+32+w];
      float w_=s_ww[mb*5+m];
      s_mem2[mb*80+k]=s_mem[mb*80+k]*(1.f-w_*er)+w_*wv2;
    }
    if(mu<25){
      int i=mu/5, j=mu-5*i;
      s_link2[mb*25+mu]=(i==j)?0.f:((1.f-s_ww[mb*5+i]-s_ww[mb*5+j])*s_link[mb*25+mu]+s_ww[mb*5+i]*s_prec[mb*5+j]);
    } else if(mu<30){
      int j=mu-25;
      s_prec2[mb*5+j]=(1.f-s_wsum[mb])*s_prec[mb*5+j]+s_ww[mb*5+j];
    }
    WB();
    // M4
    if(mu<20){
      int rr=mu/5, m=mu-5*rr;
      float nm=0.f,dt=0.f,nk=0.f;
      #pragma unroll
      for(int w=0;w<16;w++){
        float mv=s_mem2[mb*80+m*16+w], kv=s_pre[mb*112+48+rr*16+w];
        nm+=mv*mv; dt+=mv*kv; nk+=kv*kv;
      }
      float sim=dt/((sqrtf(nm)+1e-6f)*(sqrtf(nk)+1e-6f));
      s_rl[mb*20+mu]=sim*splus(XI(64+rr));
      float af=0.f, ab=0.f;
      #pragma unroll
      for(int j=0;j<5;j++) af+=s_link2[mb*25+m*5+j]*s_rwp[mb*20+rr*5+j];
      #pragma unroll
      for(int i=0;i<5;i++) ab+=s_link2[mb*25+i*5+m]*s_rwp[mb*20+rr*5+i];
      s_fwd[mb*20+rr*5+m]=af;
      s_bwd[mb*20+rr*5+m]=ab;
    }
    WB();
    // M5
    if(mu<20){
      int rr=mu/5;
      float mx=-1e30f;
      #pragma unroll
      for(int m=0;m<5;m++) mx=fmaxf(mx,s_rl[mb*20+rr*5+m]);
      float s=0.f;
      #pragma unroll
      for(int m=0;m<5;m++) s+=expf(s_rl[mb*20+rr*5+m]-mx);
      float rcw=expf(s_rl[mb*20+mu]-mx)/s;
      float q0=XI(123+3*rr),q1=XI(124+3*rr),q2=XI(125+3*rr);
      float m3=fmaxf(q0,fmaxf(q1,q2));
      float e0=expf(q0-m3),e1=expf(q1-m3),e2=expf(q2-m3);
      float inv=1.f/(e0+e1+e2);
      s_rw[mb*20+mu]=(e0*s_bwd[mb*20+mu]+e1*s_fwd[mb*20+mu]+e2*rcw)*inv;
    }
    WB();
    // M6
    for(int k=mu;k<64;k+=32){
      int rr=k>>4,w=k&15;
      float a=0.f;
      #pragma unroll
      for(int m=0;m<5;m++) a+=s_rw[mb*20+rr*5+m]*s_mem2[mb*80+m*16+w];
      rvbuf[mb*64+k]=a;
    }
    for(int k=mu;k<80;k+=32) s_mem[mb*80+k]=s_mem2[mb*80+k];
    if(mu<25) s_link[mb*25+mu]=s_link2[mb*25+mu];
    else if(mu<30) s_prec[mb*5+mu-25]=s_prec2[mb*5+mu-25];
    if(mu<20) s_rwp[mb*20+mu]=s_rw[mb*20+mu];
    if(mu>=27&&mu<32){ int m=mu-27; s_wwp[mb*5+m]=s_ww[mb*5+m]; }
    __syncthreads();

    if(tt==511){
      int cb=((g*16+r)*512+tt)*576;
      if(tid<128){
        int kg=tid>>1, e=tid&1;
        U64H4 pv; pv.u=HB[2048+(kg*16+r)*2+e];
        #pragma unroll
        for(int i=0;i<4;i++){
          float x=(float)pv.h[i];
          cat[cb+kg*8+e*4+i]=__float2bfloat16(fminf(fmaxf(x,-20.f),20.f));
        }
      }
      if(tid<64) cat[cb+512+tid]=__float2bfloat16(rvbuf[r*64+tid]);
      break;
    }

    // build lr B-frags in HB[4096..4351]
    if(tid<256){
      int kg=tid>>5, rem=tid&31, b2=rem>>1, e=rem&1;
      U64H4 pk;
      #pragma unroll
      for(int i=0;i<4;i++) pk.h[i]=(f16)rvbuf[b2*64 + kg*8+e*4+i];
      HB[4096+(kg*16+b2)*2+e]=pk.u;
    }
    __syncthreads();
    // A p2: lr chunks (prefetched weights) + register-local nonlin0
    #pragma unroll
    for(int c2=0;c2<2;c2++){
      U4H8 wf; wf.u=pfA2[c2];
      f16x8 bfr=HBv[2048+(c2*4+q4)*16+lm];
      accA=__builtin_amdgcn_mfma_f32_16x16x32_f16(wf.h,bfr,accA,0,0,0);
    }
    {
      float gi=accA[0]+em0, gf=accA[1]+em1, gg=accA[2]+em2, go=accA[3]+em3;
      float c0=sigf(gf)*c0s+sigf(gi)*tanhf(gg);
      c0s=c0;
      sh_pub[(wv*4+q4)*16+lm]=(f16)(sigf(go)*tanhf(c0));
    }
    __syncthreads();
    if(tid<128){
      int ks=tid>>4, b2=tid&15;
      U64H4 pk;
      #pragma unroll
      for(int i=0;i<4;i++) pk.h[i]=sh_pub[(ks*4+i)*16+b2];
      ast64(&GX0[g*4096+pn*2048+((4*r+(ks>>1))*16+b2)*2+(ks&1)], pk.u);
    }
    PUBF(2*tt+4);      // alpha(tt+1)

    // cover2: B p1 (Wh1 chunks) on h1(tt); cat stores; prefetch B-low frags
    f32x4 accB=(f32x4){0.f,0.f,0.f,0.f};
    #pragma unroll
    for(int c=16;c<32;c++){
      U4H8 wf; wf.u=PBv[((r*8+wv)*32+c)*64+l];
      f16x8 bfr=HBv[1024+((c-16)*4+q4)*16+lm];
      accB=__builtin_amdgcn_mfma_f32_16x16x32_f16(wf.h,bfr,accB,0,0,0);
    }
    uint4 pfB[16];
    #pragma unroll
    for(int c=0;c<16;c++) pfB[c]=PBv[((r*8+wv)*32+c)*64+l];
    {
      int cb=((g*16+r)*512+tt)*576;
      if(tid<128){
        int kg=tid>>1, e=tid&1;
        U64H4 pv; pv.u=HB[2048+(kg*16+r)*2+e];
        #pragma unroll
        for(int i=0;i<4;i++){
          float x=(float)pv.h[i];
          cat[cb+kg*8+e*4+i]=__float2bfloat16(fminf(fmaxf(x,-20.f),20.f));
        }
      }
      if(tid<64) cat[cb+512+tid]=__float2bfloat16(rvbuf[r*64+tid]);
    }

    WAITG(2*tt+4);     // alpha(tt+1)

    // B p2: stage h0(tt+1), Wi1 chunks, register-local nonlin1
    {
      u64 s0=ald64(&GX0[g*4096+pn*2048+tid      ]);
      u64 s1=ald64(&GX0[g*4096+pn*2048+tid+512  ]);
      u64 s2=ald64(&GX0[g*4096+pn*2048+tid+1024 ]);
      u64 s3=ald64(&GX0[g*4096+pn*2048+tid+1536 ]);
      HB[tid]=s0; HB[tid+512]=s1; HB[tid+1024]=s2; HB[tid+1536]=s3;
    }
    __syncthreads();
    #pragma unroll
    for(int c=0;c<16;c++){
      U4H8 wf; wf.u=pfB[c];
      f16x8 bfr=HBv[(c*4+q4)*16+lm];
      accB=__builtin_amdgcn_mfma_f32_16x16x32_f16(wf.h,bfr,accB,0,0,0);
    }
    {
      float gi=accB[0]+b1Li, gf=accB[1]+b1Lf, gg=accB[2]+b1Lg, go=accB[3]+b1Lo;
      float c1=sigf(gf)*c1s+sigf(gi)*tanhf(gg);
      c1s=c1;
      sh_pub[(wv*4+q4)*16+lm]=(f16)(sigf(go)*tanhf(c1));
    }
    __syncthreads();
    if(tid<128){
      int ks=tid>>4, b2=tid&15;
      U64H4 pk;
      #pragma unroll
      for(int i=0;i<4;i++) pk.h[i]=sh_pub[(ks*4+i)*16+b2];
      ast64(&GX1[g*4096+pn*2048+((4*r+(ks>>1))*16+b2)*2+(ks&1)], pk.u);
    }
    PUBF(2*tt+5);      // beta(tt+1)
  }
#undef WAITG
#undef PUBF
#undef XI
#undef WB
}

// ---------------- final output GEMM (f32 out) ----------------
__global__ void __launch_bounds__(256) k_out(const bf16* __restrict__ cat,
                                             const float* __restrict__ Wc,
                                             const float* __restrict__ bc,
                                             float* __restrict__ outp){
  int t0=blockIdx.x*64, v0=blockIdx.y*64, b=blockIdx.z;
  __shared__ float As[64][33];
  __shared__ float Bs[32][65];
  int tid=threadIdx.x;
  int ti=tid>>4, vi=tid&15;
  float acc[4][4]={};
  for(int k0=0;k0<576;k0+=32){
    for(int i=tid;i<64*32;i+=256){
      int rr=i>>5,k=i&31;
      As[rr][k]=b2f(cat[(b*512+t0+rr)*576+k0+k]);
    }
    for(int i=tid;i<64*32;i+=256){
      int v=i>>5,k=i&31;
      Bs[k][v]=Wc[(v0+v)*576+k0+k];
    }
    __syncthreads();
    #pragma unroll 8
    for(int kk=0;kk<32;kk++){
      float av[4],bv[4];
      #pragma unroll
      for(int x=0;x<4;x++) av[x]=As[ti*4+x][kk];
      #pragma unroll
      for(int y=0;y<4;y++) bv[y]=Bs[kk][vi*4+y];
      #pragma unroll
      for(int x=0;x<4;x++)
        #pragma unroll
        for(int y=0;y<4;y++) acc[x][y]+=av[x]*bv[y];
    }
    __syncthreads();
  }
  #pragma unroll
  for(int y=0;y<4;y++){
    int v=v0+vi*4+y;
    float bcv=bc[v];
    #pragma unroll
    for(int x=0;x<4;x++){
      int tt=t0+ti*4+x;
      outp[(b*256+v)*512+tt]=acc[x][y]+bcv;
    }
  }
}

extern "C" void kernel_launch(void* const* d_in, const int* in_sizes, int n_in,
                              void* d_out, int out_size, void* d_ws, size_t ws_size,
                              hipStream_t stream) {
  const int*  tokens = (const int*) d_in[0];
  const void* emb    = d_in[1];
  const void* Wi0    = d_in[2];
  const void* Wh0    = d_in[3];
  const void* b0     = d_in[4];
  const void* Wi1    = d_in[5];
  const void* Wh1    = d_in[6];
  const void* b1     = d_in[7];
  const void* W_if   = d_in[8];
  const void* b_if   = d_in[9];
  const void* W_out  = d_in[10];
  const void* b_out  = d_in[11];
  const void* W_fc   = d_in[12];
  const void* b_fc   = d_in[13];

  static const int expect[14] = {64*512, 256*512, 2048*576, 2048*512, 2048,
                                 2048*512, 2048*512, 2048, 135*512, 135,
                                 512*576, 512, 256*512, 256};
  bool ok = (n_in == 14);
  if(ok) for(int i=0;i<14;i++) if(in_sizes[i]!=expect[i]) ok=false;

  int*      flags = (int*)d_ws;                   // [0]=dtype flag
  float*    embW  = (float*)d_ws + 64;            // 2048*256
  ushort_t* PA    = (ushort_t*)(embW + 524288);   // 1179648 f16 used (region 1310720; FL at +1179648)
  ushort_t* PB    = PA + 1310720;                 // 2097152 f16
  float*    Wreg  = (float*)(PB + 2097152);       // PW (73728 f16) lives here
  float*    b_ifF = Wreg + 69632;                 // 160
  float*    Wc    = b_ifF + 160;                  // 147456
  float*    bc    = Wc + 147456;                  // 256
  u64*      GX0   = (u64*)(bc + 256);             // 16384 u64 = [4 grp][2 ph][2048]
  u64*      GX1   = GX0 + 16384;                  // 16384 u64
  u64*      GXL   = GX1 + 16384;                  // 2048 u64 (unused, layout keep)
  bf16*     cat   = (bf16*)(GXL + 2048);          // 64*512*576
  unsigned* FL    = (unsigned*)(PA + 1179648);    // 64 dwords: 4 groups x 16 flags
  ushort_t* PW    = (ushort_t*)Wreg;              // 73728 f16

  size_t need = 9783168ull + 278528ull + 37748736ull;   // = 47,810,432 B
  if(!ok || ws_size < need){
    hipMemsetAsync(d_out, 0, (size_t)out_size*4, stream);
    return;
  }

  k_detect<<<dim3(1), dim3(256), 0, stream>>>(emb, flags);
  k_embW<<<dim3(2048), dim3(256), 0, stream>>>(emb, Wi0, b0, flags, embW);
  k_wpkA<<<dim3(4608), dim3(256), 0, stream>>>(Wh0, Wi0, flags, PA);
  k_wpkB<<<dim3(8192), dim3(256), 0, stream>>>(Wi1, Wh1, flags, PB);
  k_wifP<<<dim3(288), dim3(256), 0, stream>>>(W_if, b_if, flags, PW, b_ifF, FL);
  k_wc  <<<dim3(576),  dim3(256), 0, stream>>>(W_fc, W_out, b_out, b_fc, flags, Wc, bc);

  void* kargs[] = {
    (void*)&tokens, (void*)&b1, (void*)&flags,
    (void*)&embW, (void*)&PA, (void*)&PB,
    (void*)&PW, (void*)&b_ifF,
    (void*)&GX0, (void*)&GX1, (void*)&FL,
    (void*)&cat
  };
  hipLaunchCooperativeKernel((const void*)k_dnc3, dim3(64), dim3(512), kargs, 0, stream);

  k_out<<<dim3(8,4,64), dim3(256), 0, stream>>>(cat, Wc, bc, (float*)d_out);
}